// Round 10
// baseline (161.883 us; speedup 1.0000x reference)
//
#include <hip/hip_runtime.h>

typedef unsigned short ushort_t;
typedef __attribute__((ext_vector_type(8))) short bf16x8;
typedef __attribute__((ext_vector_type(8))) _Float16 f16x8;
typedef __attribute__((ext_vector_type(16))) float f32x16;

#define NORMC 0.35355339059327373f   // 64^-0.25
#define DIAGC 0.0625f                // 0.5 * 64^-0.5
#define RATIO 0.0625f                // 256^-0.5
#define KEPS  1e-4f
#define AEPS  1e-6f
#define KAPPA (RATIO*KEPS)

__device__ __forceinline__ unsigned short f2bf(float f){
  unsigned u = __float_as_uint(f);
  unsigned r = (u + 0x7FFFu + ((u >> 16) & 1u)) >> 16;  // RNE
  return (unsigned short)r;
}
__device__ __forceinline__ float bf2f(unsigned short h){
  return __uint_as_float(((unsigned)h) << 16);
}
__device__ __forceinline__ unsigned enc_f(float f){
  unsigned u = __float_as_uint(f);
  return (u & 0x80000000u) ? ~u : (u | 0x80000000u);
}
__device__ __forceinline__ float dec_f(unsigned e){
  unsigned b = (e & 0x80000000u) ? (e ^ 0x80000000u) : ~e;
  return __uint_as_float(b);
}
__device__ __forceinline__ unsigned short h2u(_Float16 h){
  union { _Float16 h; unsigned short u; } c; c.h = h; return c.u;
}
__device__ __forceinline__ unsigned pk2h(float a, float b){
  return (unsigned)h2u((_Float16)a) | ((unsigned)h2u((_Float16)b) << 16);
}

// K0: proj -> fp16 (NORMC-scaled), layout [m][d]; init global-max slot
__global__ void k_prep(const float* __restrict__ proj, ushort_t* __restrict__ pjh,
                       unsigned* __restrict__ kmax){
  int t = threadIdx.x;   // m
  if (t == 0) *kmax = 0u;
  for (int d = 0; d < 64; ++d){
    float val = NORMC * proj[t*64 + d];
    pjh[t*64 + d] = h2u((_Float16)val);
  }
}

// K_A: k-feature GEMM + per-chunk sums (fused). One block per chunk, 512 thr / 8 waves.
// Writes kfpre (global), Sl_pre [e][m] (fp32), Zl_pre [m], vsum [e], lmArr, atomicMax gm.
__launch_bounds__(512, 2)
__global__ void k_chunkF(const float* __restrict__ kk, const float* __restrict__ v,
                         const ushort_t* __restrict__ pjh,
                         ushort_t* __restrict__ kfp, float* __restrict__ Zl,
                         float* __restrict__ Sl, float* __restrict__ vsb,
                         unsigned* __restrict__ kmax, float* __restrict__ lmArr)
{
  extern __shared__ char sm[];
  char* Bp = sm;                        // proj frag-packed [0,32K)
  char* Xh = sm + 32768;                // x-hi frags [32K,48K)
  char* Xl = sm + 49152;                // x-lo frags [48K,64K)
  char* ob = sm;                        // epilogue kfp staging alias [0,64K)
  char* kT = sm + 65536;                // [256 m][256B c] bf16, swz ^((m&15)<<4)
  char* vT = sm + 131072;               // [64 e][256B c] bf16, swz ^((e&15)<<4)
  float* dsm  = (float*)(sm + 147456);  // [128]
  float* wred = (float*)(sm + 147968);  // [8]

  int tid = threadIdx.x;
  int w   = tid >> 6;
  int wr  = w & 3;
  int wc  = w >> 2;
  int lane= tid & 63;
  int l31 = lane & 31;
  int half= lane >> 5;
  int cb  = (int)blockIdx.x;
  int bh  = cb >> 5, j = cb & 31;
  int row0 = bh*4096 + j*128;

  // stage proj frags
  for (int i = tid; i < 2048; i += 512){
    int m = i >> 3, c8 = i & 7;
    int rgn = ((m>>5)*4 + (c8>>1))*2 + (c8&1);
    int slot = (m & 31) ^ ((rgn & 7) << 2);
    *(uint4*)(Bp + rgn*512 + slot*16) = *(const uint4*)(pjh + m*64 + c8*8);
  }
  // stage x = k-chunk frags (fp16 hi/lo) + dsm
  #pragma unroll
  for (int it = 0; it < 4; ++it){
    int g = it*512 + tid;
    int row = g >> 4, c4 = g & 15;
    float4 xv = *(const float4*)(kk + (size_t)(row0+row)*64 + c4*4);
    _Float16 h0=(_Float16)xv.x, h1=(_Float16)xv.y, h2=(_Float16)xv.z, h3=(_Float16)xv.w;
    float l0 = xv.x-(float)h0, l1 = xv.y-(float)h1, l2 = xv.z-(float)h2, l3 = xv.w-(float)h3;
    int rgn = ((row>>5)*4 + (c4>>2))*2 + ((c4>>1)&1);
    int off = rgn*512 + (((row&31) ^ ((c4>>1)<<2)))*16 + (c4&1)*8;
    uint2 ph; ph.x = (unsigned)h2u(h0)|((unsigned)h2u(h1)<<16);
              ph.y = (unsigned)h2u(h2)|((unsigned)h2u(h3)<<16);
    uint2 pl; pl.x = pk2h(l0,l1); pl.y = pk2h(l2,l3);
    *(uint2*)(Xh + off) = ph;
    *(uint2*)(Xl + off) = pl;
    float ssq = xv.x*xv.x + xv.y*xv.y + xv.z*xv.z + xv.w*xv.w;
    ssq += __shfl_xor(ssq, 1); ssq += __shfl_xor(ssq, 2);
    ssq += __shfl_xor(ssq, 4); ssq += __shfl_xor(ssq, 8);
    if ((tid & 15) == 0) dsm[row] = ssq;
  }
  // stage vT (bf16 transposed)
  {
    int e = tid & 63, c0 = tid >> 6;
    int swz = (e & 15) << 4;
    #pragma unroll
    for (int u=0; u<16; ++u){
      int c = c0 + u*8;
      *(ushort_t*)(vT + e*256 + ((c*2) ^ swz)) = f2bf(v[(size_t)(row0+c)*64 + e]);
    }
  }
  __syncthreads();

  // k-dash (fp16 2-term)
  f16x8 ah[4], al[4];
  #pragma unroll
  for (int ks = 0; ks < 4; ++ks){
    int rgn = (wr*4+ks)*2+half;
    int off = rgn*512 + ((l31 ^ ((2*ks+half)<<2)))*16;
    ah[ks] = *(const f16x8*)(Xh + off);
    al[ks] = *(const f16x8*)(Xl + off);
  }
  f32x16 acc[4];
  #pragma unroll
  for (int ct=0; ct<4; ++ct){
    #pragma unroll
    for (int r=0; r<16; ++r) acc[ct][r] = 0.f;
  }
  #pragma unroll
  for (int ks = 0; ks < 4; ++ks){
    #pragma unroll
    for (int ct=0; ct<4; ++ct){
      int ctg = wc*4 + ct;
      int rgn = (ctg*4+ks)*2+half;
      f16x8 bv = *(const f16x8*)(Bp + rgn*512 + ((l31 ^ ((2*ks+half)<<2)))*16);
      acc[ct] = __builtin_amdgcn_mfma_f32_32x32x16_f16(ah[ks], bv, acc[ct], 0, 0, 0);
      acc[ct] = __builtin_amdgcn_mfma_f32_32x32x16_f16(al[ks], bv, acc[ct], 0, 0, 0);
    }
  }

  // block max
  {
    float wm = acc[0][0];
    #pragma unroll
    for (int ct=0; ct<4; ++ct){
      #pragma unroll
      for (int r=0; r<16; ++r) wm = fmaxf(wm, acc[ct][r]);
    }
    #pragma unroll
    for (int s=1; s<32; s<<=1) wm = fmaxf(wm, __shfl_xor(wm, s));
    wm = fmaxf(wm, __shfl_xor(wm, 32));
    if (lane == 0) wred[w] = wm;
  }
  __syncthreads();
  float lmb = wred[0];
  #pragma unroll
  for (int i=1;i<8;++i) lmb = fmaxf(lmb, wred[i]);
  if (tid == 0){
    lmArr[cb] = lmb;
    atomicMax(kmax, enc_f(lmb));
  }
  float dgv[16];
  #pragma unroll
  for (int r=0; r<16; ++r)
    dgv[r] = DIAGC * dsm[32*wr + (r&3) + 8*(r>>2) + 4*half];

  // epilogue: kfpre -> ob (for global store) and kT (transposed, for GEMM)
  #pragma unroll
  for (int ct=0; ct<4; ++ct){
    int m = wc*128 + ct*32 + l31;
    int swm = (m & 15) << 4;
    #pragma unroll
    for (int g=0; g<4; ++g){
      unsigned pk0=0, pk1=0;
      #pragma unroll
      for (int rr=0; rr<4; ++rr){
        int r = g*4 + rr;
        int c = 32*wr + rr + 8*g + 4*half;
        float e = __expf(acc[ct][r] - dgv[r] - lmb);
        unsigned b = f2bf(e);
        if (rr < 2) pk0 |= b << (16*rr); else pk1 |= b << (16*(rr-2));
        *(ushort_t*)(ob + c*512 + ((m*2) ^ ((c&15)<<4))) = (ushort_t)b;
      }
      int c0 = 32*wr + 8*g + 4*half;
      *(uint2*)(kT + m*256 + ((c0*2) ^ swm)) = make_uint2(pk0, pk1);
    }
  }
  __syncthreads();

  // GEMM (swapped orientation): Sl_pre[e][m] = sum_c v[e][c]*kfpre[m][c];
  // Zl_pre[m] via ones-B on kT rows; vsum[e] via ones-A (wave 0).
  f32x16 accS[2], accz, avs[2];
  #pragma unroll
  for (int et=0;et<2;++et){
    #pragma unroll
    for (int r=0;r<16;++r){ accS[et][r]=0.f; avs[et][r]=0.f; }
  }
  #pragma unroll
  for (int r=0;r<16;++r) accz[r]=0.f;
  bf16x8 onesB, onesA;
  #pragma unroll
  for (int i=0;i<8;++i){
    onesB[i] = (l31==0) ? (short)0x3F80 : (short)0;
    onesA[i] = (short)0x3F80;
  }
  int erow = (w&1)*32 + l31;
  int mc0  = ((w>>1)*2 + 0)*32 + l31;
  int mc1  = ((w>>1)*2 + 1)*32 + l31;
  int mrow = 32*w + l31;
  #pragma unroll
  for (int ks=0; ks<8; ++ks){
    int koff = ks*32 + half*16;
    bf16x8 afv = *(const bf16x8*)(vT + erow*256 + (koff ^ ((erow&15)<<4)));
    bf16x8 bk0 = *(const bf16x8*)(kT + mc0*256 + (koff ^ ((mc0&15)<<4)));
    bf16x8 bk1 = *(const bf16x8*)(kT + mc1*256 + (koff ^ ((mc1&15)<<4)));
    bf16x8 afk = *(const bf16x8*)(kT + mrow*256 + (koff ^ ((mrow&15)<<4)));
    accS[0] = __builtin_amdgcn_mfma_f32_32x32x16_bf16(afv, bk0, accS[0], 0, 0, 0);
    accS[1] = __builtin_amdgcn_mfma_f32_32x32x16_bf16(afv, bk1, accS[1], 0, 0, 0);
    accz    = __builtin_amdgcn_mfma_f32_32x32x16_bf16(afk, onesB, accz, 0, 0, 0);
    if (w == 0){
      bf16x8 bv1 = *(const bf16x8*)(vT + (32+l31)*256 + (koff ^ (((32+l31)&15)<<4)));
      avs[0] = __builtin_amdgcn_mfma_f32_32x32x16_bf16(onesA, afv, avs[0], 0, 0, 0);
      avs[1] = __builtin_amdgcn_mfma_f32_32x32x16_bf16(onesA, bv1, avs[1], 0, 0, 0);
    }
  }
  // stores: Sl [e][m] coalesced over l31
  #pragma unroll
  for (int r=0; r<16; ++r){
    int e = (w&1)*32 + (r&3) + 8*(r>>2) + 4*half;
    Sl[(size_t)cb*16384 + (size_t)e*256 + ((w>>1)*2+0)*32 + l31] = accS[0][r];
    Sl[(size_t)cb*16384 + (size_t)e*256 + ((w>>1)*2+1)*32 + l31] = accS[1][r];
  }
  if (l31 == 0){
    #pragma unroll
    for (int r=0; r<16; ++r){
      int m = 32*w + (r&3) + 8*(r>>2) + 4*half;
      Zl[(size_t)cb*256 + m] = accz[r];
    }
  }
  if (w == 0 && half == 0){
    vsb[(size_t)cb*64 + l31]      = avs[0][0];
    vsb[(size_t)cb*64 + 32 + l31] = avs[1][0];
  }
  // kfp global store from ob
  {
    ushort_t* dst = kfp + (size_t)row0*256;
    for (int i = tid; i < 4096; i += 512){
      int row = i >> 5, s = i & 31;
      uint4 d = *(const uint4*)(ob + row*512 + ((s*16) ^ ((row&15)<<4)));
      *(uint4*)(dst + (size_t)row*256 + ((s ^ (row&15)))*8) = d;
    }
  }
}

// K4: scan with alpha/kappa correction. Sl layout [cb][e][m]. grid 16*65.
// Writes S0b bf16 [pb][e][m], outSt fp32 [bh][e][m] (inclusive), Zl excl in place, outZ.
__launch_bounds__(256)
__global__ void k_scan(float* __restrict__ Zl, const float* __restrict__ Sl,
                       const float* __restrict__ vsb, const float* __restrict__ lmArr,
                       const unsigned* __restrict__ kmax,
                       ushort_t* __restrict__ S0b,
                       float* __restrict__ outZ, float* __restrict__ outSt){
  float gm = dec_f(*kmax);
  int t = threadIdx.x;
  int bh = blockIdx.x / 65;
  int s  = blockIdx.x % 65;
  if (s == 64){
    size_t base = (size_t)(bh*32)*256 + t;
    float rz = 0.f;
    #pragma unroll
    for (int j0=0;j0<32;j0+=8){
      float x[8];
      #pragma unroll
      for (int u=0;u<8;++u){
        int cbx = bh*32 + j0 + u;
        float a = RATIO * __expf(lmArr[cbx] - gm);
        x[u] = fmaf(a, Zl[base + (size_t)(j0+u)*256], KAPPA*128.f);
      }
      #pragma unroll
      for (int u=0;u<8;++u){ Zl[base + (size_t)(j0+u)*256] = rz; rz += x[u]; }
    }
    outZ[(size_t)bh*256 + t] = rz;
  } else {
    // e = s (uniform), m = t
    size_t base = (size_t)(bh*32)*16384 + (size_t)s*256 + t;
    float rs = 0.f;
    #pragma unroll
    for (int j0=0;j0<32;j0+=8){
      float x[8];
      #pragma unroll
      for (int u=0;u<8;++u){
        int cbx = bh*32 + j0 + u;
        float a = RATIO * __expf(lmArr[cbx] - gm);
        x[u] = fmaf(a, Sl[base + (size_t)(j0+u)*16384], KAPPA * vsb[(size_t)cbx*64 + s]);
      }
      #pragma unroll
      for (int u=0;u<8;++u){
        S0b[(size_t)(bh*32 + j0+u)*16384 + (size_t)s*256 + t] = f2bf(rs);
        rs += x[u];
      }
    }
    outSt[(size_t)bh*16384 + (size_t)s*256 + t] = rs;
  }
}

// K_TR: outSt [bh][e][m] -> outS [bh][m][e]. grid 64 (16 bh x 4 m-tiles).
__launch_bounds__(256)
__global__ void k_tr(const float* __restrict__ outSt, float* __restrict__ outS){
  __shared__ float tl[64][65];
  int tid = threadIdx.x;
  int bh = blockIdx.x >> 2, mt = blockIdx.x & 3;
  int m0 = mt*64;
  for (int i = tid; i < 4096; i += 256){
    int e = i >> 6, m = i & 63;
    tl[e][m] = outSt[(size_t)bh*16384 + (size_t)e*256 + m0 + m];
  }
  __syncthreads();
  for (int i = tid; i < 4096; i += 256){
    int m = i >> 6, e = i & 63;
    outS[(size_t)bh*16384 + (size_t)(m0+m)*64 + e] = tl[e][m];
  }
}

// K_B: q-feature GEMM + per-chunk output (fused, slim staging).
__launch_bounds__(512, 4)
__global__ void k_outF(const float* __restrict__ q, const ushort_t* __restrict__ pjh,
                       const ushort_t* __restrict__ kfp, const float* __restrict__ v,
                       const ushort_t* __restrict__ S0b, const float* __restrict__ Zp,
                       const float* __restrict__ lmArr, const unsigned* __restrict__ kmax,
                       float* __restrict__ outO)
{
  extern __shared__ char sm[];
  char* Bp   = sm;                      // [0,32K) dash proj; Ab alias after
  char* Ab   = sm;                      // [128][256B] bf16, swz ^((r&15)<<4)
  char* Xh   = sm + 32768;              // [32K,48K); qft / vTb alias
  char* qft  = sm + 32768;              // [128 c][128B m-tile], swz ^((c&7)<<4)
  char* vTb  = sm + 32768;              // [64 e][256B c], swz ^((e&15)<<4)
  char* Xl   = sm + 49152;              // [48K,64K); ktb alias
  char* ktb  = sm + 49152;              // [128 i][128B m-tile], swz ^((i&7)<<4)
  char* s0t  = sm + 65536;              // [64 e][128B m-tile], swz ^((e&7)<<4)
  float* dsm = (float*)(sm + 73728);    // [128]
  float* rmx = (float*)(sm + 74240);    // [2][128]
  float* rsc = (float*)(sm + 75264);    // [2][128]
  ushort_t* z0b = (ushort_t*)(sm + 76288); // [256] bf16(Z0+eps)

  int tid = threadIdx.x;
  int w   = tid >> 6;
  int wr  = w & 3;
  int wc  = w >> 2;
  int lane= tid & 63;
  int l31 = lane & 31;
  int half= lane >> 5;
  int pb  = (int)blockIdx.x;
  int bh  = pb >> 5, j = pb & 31;
  int row0 = bh*4096 + j*128;
  size_t qbase = (size_t)row0*256;

  float gmv = dec_f(*kmax);
  float alpha = RATIO * __expf(lmArr[pb] - gmv);

  // phase 1: stage proj + q frags + dsm + z0b
  for (int i = tid; i < 2048; i += 512){
    int m = i >> 3, c8 = i & 7;
    int rgn = ((m>>5)*4 + (c8>>1))*2 + (c8&1);
    int slot = (m & 31) ^ ((rgn & 7) << 2);
    *(uint4*)(Bp + rgn*512 + slot*16) = *(const uint4*)(pjh + m*64 + c8*8);
  }
  #pragma unroll
  for (int it = 0; it < 4; ++it){
    int g = it*512 + tid;
    int row = g >> 4, c4 = g & 15;
    float4 xv = *(const float4*)(q + (size_t)(row0+row)*64 + c4*4);
    _Float16 h0=(_Float16)xv.x, h1=(_Float16)xv.y, h2=(_Float16)xv.z, h3=(_Float16)xv.w;
    float l0 = xv.x-(float)h0, l1 = xv.y-(float)h1, l2 = xv.z-(float)h2, l3 = xv.w-(float)h3;
    int rgn = ((row>>5)*4 + (c4>>2))*2 + ((c4>>1)&1);
    int off = rgn*512 + (((row&31) ^ ((c4>>1)<<2)))*16 + (c4&1)*8;
    uint2 ph; ph.x = (unsigned)h2u(h0)|((unsigned)h2u(h1)<<16);
              ph.y = (unsigned)h2u(h2)|((unsigned)h2u(h3)<<16);
    uint2 pl; pl.x = pk2h(l0,l1); pl.y = pk2h(l2,l3);
    *(uint2*)(Xh + off) = ph;
    *(uint2*)(Xl + off) = pl;
    float ssq = xv.x*xv.x + xv.y*xv.y + xv.z*xv.z + xv.w*xv.w;
    ssq += __shfl_xor(ssq, 1); ssq += __shfl_xor(ssq, 2);
    ssq += __shfl_xor(ssq, 4); ssq += __shfl_xor(ssq, 8);
    if ((tid & 15) == 0) dsm[row] = ssq;
  }
  if (tid < 256) z0b[tid] = f2bf(Zp[(size_t)pb*256 + tid] + AEPS);
  __syncthreads();

  // q-dash
  f16x8 ah[4], al[4];
  #pragma unroll
  for (int ks = 0; ks < 4; ++ks){
    int rgn = (wr*4+ks)*2+half;
    int off = rgn*512 + ((l31 ^ ((2*ks+half)<<2)))*16;
    ah[ks] = *(const f16x8*)(Xh + off);
    al[ks] = *(const f16x8*)(Xl + off);
  }
  f32x16 acc[4];
  #pragma unroll
  for (int ct=0; ct<4; ++ct){
    #pragma unroll
    for (int r=0; r<16; ++r) acc[ct][r] = 0.f;
  }
  #pragma unroll
  for (int ks = 0; ks < 4; ++ks){
    #pragma unroll
    for (int ct=0; ct<4; ++ct){
      int ctg = wc*4 + ct;
      int rgn = (ctg*4+ks)*2+half;
      f16x8 bv = *(const f16x8*)(Bp + rgn*512 + ((l31 ^ ((2*ks+half)<<2)))*16);
      acc[ct] = __builtin_amdgcn_mfma_f32_32x32x16_f16(ah[ks], bv, acc[ct], 0, 0, 0);
      acc[ct] = __builtin_amdgcn_mfma_f32_32x32x16_f16(al[ks], bv, acc[ct], 0, 0, 0);
    }
  }
  // per-row max over this wave's 128 cols -> rmx
  {
    float rmax[16];
    #pragma unroll
    for (int r=0; r<16; ++r){
      float mx = acc[0][r];
      #pragma unroll
      for (int ct=1; ct<4; ++ct) mx = fmaxf(mx, acc[ct][r]);
      #pragma unroll
      for (int s=1; s<32; s<<=1) mx = fmaxf(mx, __shfl_xor(mx, s));
      rmax[r] = mx;
    }
    if (l31 == 0){
      #pragma unroll
      for (int r=0; r<16; ++r)
        rmx[wc*128 + 32*wr + (r&3) + 8*(r>>2) + 4*half] = rmax[r];
    }
  }
  __syncthreads();

  // exp all 256 cols -> packed bf16 regs (acc dies here)
  unsigned qpk[2][16];
  #pragma unroll
  for (int r=0; r<16; ++r){
    int lrow = 32*wr + (r&3) + 8*(r>>2) + 4*half;
    float dg = DIAGC * dsm[lrow];
    float st = fmaxf(rmx[lrow], rmx[128+lrow]);
    #pragma unroll
    for (int p=0; p<2; ++p){
      float e0 = __expf(acc[2*p][r]   - dg - st);
      float e1 = __expf(acc[2*p+1][r] - dg - st);
      qpk[p][r] = (unsigned)f2bf(RATIO*(e0+KEPS)) |
                  ((unsigned)f2bf(RATIO*(e1+KEPS)) << 16);
    }
  }

  // m-loop: A_pre = qf*kfpre^T (triangle), acc2 = qf*S0, accQ = qf*[z0|ones]
  // FULLY UNROLLED: qpk indices must be compile-time (rule #20 — R9's regression).
  f32x16 accA[2], acc2, accQ;
  #pragma unroll
  for (int ct2=0;ct2<2;++ct2){
    #pragma unroll
    for (int r=0;r<16;++r) accA[ct2][r] = 0.f;
  }
  #pragma unroll
  for (int r=0;r<16;++r){ acc2[r] = 0.f; accQ[r] = 0.f; }

  int arow = 32*wr + l31;
  #pragma unroll
  for (int mt=0; mt<4; ++mt){
    int m0 = mt*64;
    __syncthreads();
    // ktb: raw kfpre uint4 copies
    #pragma unroll
    for (int u=0;u<2;++u){
      int ci = tid*2+u; int rr = ci>>3, c8 = ci&7;
      *(uint4*)(ktb + rr*128 + ((c8*16) ^ ((rr&7)<<4))) =
          *(const uint4*)(kfp + qbase + (size_t)rr*256 + m0 + c8*8);
    }
    // s0t: S0b [e][m] uint4 copies
    {
      int e = tid >> 3, c8 = tid & 7;
      *(uint4*)(s0t + e*128 + ((c8*16) ^ ((e&7)<<4))) =
          *(const uint4*)(S0b + (size_t)pb*16384 + (size_t)e*256 + m0 + c8*8);
    }
    // qf tile from packed regs (waves owning these cols); p = mt&1 is static now
    if (wc == (mt>>1)){
      #pragma unroll
      for (int r=0;r<16;++r){
        int c = 32*wr + (r&3) + 8*(r>>2) + 4*half;
        int sw = (c&7)<<4;
        *(ushort_t*)(qft + c*128 + ((l31*2) ^ sw))      = (ushort_t)(qpk[mt&1][r] & 0xffffu);
        *(ushort_t*)(qft + c*128 + (((32+l31)*2) ^ sw)) = (ushort_t)(qpk[mt&1][r] >> 16);
      }
    }
    __syncthreads();
    #pragma unroll
    for (int ks=0;ks<4;++ks){
      int ko = ks*32 + half*16;
      bf16x8 af = *(const bf16x8*)(qft + arow*128 + (ko ^ ((arow&7)<<4)));
      {
        int er = wc*32 + l31;
        bf16x8 bS = *(const bf16x8*)(s0t + er*128 + (ko ^ ((er&7)<<4)));
        acc2 = __builtin_amdgcn_mfma_f32_32x32x16_bf16(af, bS, acc2, 0, 0, 0);
      }
      {
        bf16x8 zb = {};
        if (l31 == 0) zb = *(const bf16x8*)((const char*)z0b + m0*2 + ko);
        if (l31 == 1){
          #pragma unroll
          for (int i2=0;i2<8;++i2) zb[i2] = (short)0x3F80;
        }
        accQ = __builtin_amdgcn_mfma_f32_32x32x16_bf16(af, zb, accQ, 0, 0, 0);
      }
      #pragma unroll
      for (int ct2=0;ct2<2;++ct2){
        int c = wc*2 + ct2;
        if (c <= wr){
          int br = c*32 + l31;
          bf16x8 bk = *(const bf16x8*)(ktb + br*128 + (ko ^ ((br&7)<<4)));
          accA[ct2] = __builtin_amdgcn_mfma_f32_32x32x16_bf16(af, bk, accA[ct2], 0, 0, 0);
        }
      }
    }
  }

  // extract qz / qfs per row from accQ (cols 0,1 of D)
  float qzv[16], qfsv[16];
  #pragma unroll
  for (int r=0;r<16;++r){
    qzv[r]  = __shfl(accQ[r], half*32 + 0);
    qfsv[r] = __shfl(accQ[r], half*32 + 1);
  }

  // mask + correct A, rowsums, write Ab bf16
  {
    float p[16];
    #pragma unroll
    for (int r=0;r<16;++r) p[r]=0.f;
    #pragma unroll
    for (int ct2=0;ct2<2;++ct2){
      int c = wc*2 + ct2;
      if (c <= wr){
        #pragma unroll
        for (int r=0;r<16;++r){
          int grow = 32*wr + (r&3) + 8*(r>>2) + 4*half;
          int col  = c*32 + l31;
          float mval = (col <= grow) ? fmaf(alpha, accA[ct2][r], KAPPA*qfsv[r]) : 0.f;
          p[r] += mval;
          *(ushort_t*)(Ab + grow*256 + ((col*2) ^ ((grow&15)<<4))) = f2bf(mval);
        }
      }
    }
    #pragma unroll
    for (int s2=1;s2<32;s2<<=1){
      #pragma unroll
      for (int r=0;r<16;++r) p[r] += __shfl_xor(p[r], s2);
    }
    if (l31 == 0){
      #pragma unroll
      for (int r=0;r<16;++r)
        rsc[wc*128 + 32*wr + (r&3) + 8*(r>>2) + 4*half] = p[r];
    }
  }
  __syncthreads();

  // stage vTb (over dead qft/ktb)
  {
    int e = tid & 63, c0 = tid >> 6;
    int swz = (e & 15) << 4;
    #pragma unroll
    for (int u=0; u<16; ++u){
      int c = c0 + u*8;
      *(ushort_t*)(vTb + e*256 + ((c*2) ^ swz)) = f2bf(v[(size_t)(row0+c)*64 + e]);
    }
  }
  __syncthreads();

  // A*v (triangle over ks)
  #pragma unroll
  for (int ks=0; ks<8; ++ks){
    if (ks <= 2*wr + 1){
      bf16x8 af = *(const bf16x8*)(Ab + arow*256 + ((ks*32 + half*16) ^ ((arow&15)<<4)));
      int er = wc*32 + l31;
      bf16x8 bv = *(const bf16x8*)(vTb + er*256 + ((ks*32 + half*16) ^ ((er&15)<<4)));
      acc2 = __builtin_amdgcn_mfma_f32_32x32x16_bf16(af, bv, acc2, 0, 0, 0);
    }
  }

  // epilogue: divide & store
  #pragma unroll
  for (int r=0;r<16;++r){
    int grow = 32*wr + (r&3) + 8*(r>>2) + 4*half;
    float dv = 1.0f / (rsc[grow] + rsc[128+grow] + qzv[r]);
    outO[(size_t)(row0+grow)*64 + wc*32 + l31] = acc2[r] * dv;
  }
}

extern "C" void kernel_launch(void* const* d_in, const int* in_sizes, int n_in,
                              void* d_out, int out_size, void* d_ws, size_t ws_size,
                              hipStream_t stream){
  (void)in_sizes; (void)n_in; (void)out_size; (void)ws_size;
  const float* q    = (const float*)d_in[0];
  const float* k    = (const float*)d_in[1];
  const float* v    = (const float*)d_in[2];
  const float* proj = (const float*)d_in[3];

  char* ws = (char*)d_ws;
  unsigned* kmax = (unsigned*)ws;                          // @0
  float*    lmA  = (float*)(ws + 256);                     // 2048 B
  ushort_t* pjh  = (ushort_t*)(ws + 4096);                 // 32768 B
  ushort_t* kfp  = (ushort_t*)(ws + 65792);                // 33,554,432
  float*    Zl   = (float*)(ws + 33620224);                // 524,288
  float*    Sl   = (float*)(ws + 34144512);                // 33,554,432 ([cb][e][m])
  ushort_t* S0b  = (ushort_t*)(ws + 67698944);             // 16,777,216 ([pb][e][m])
  float*    vsb  = (float*)(ws + 84476160);                // 131,072
  float*    oSt  = (float*)(ws + 84607232);                // 4,194,304 ([bh][e][m])

  float* outO = (float*)d_out;
  float* outZ = outO + (size_t)2*8*4096*64;
  float* outS = outZ + 2*8*256;

  hipFuncSetAttribute((const void*)k_chunkF, hipFuncAttributeMaxDynamicSharedMemorySize, 148480);
  hipFuncSetAttribute((const void*)k_outF,   hipFuncAttributeMaxDynamicSharedMemorySize, 76800);

  k_prep  <<<1,     256, 0, stream>>>(proj, pjh, kmax);
  k_chunkF<<<512,   512, 148480, stream>>>(k, v, pjh, kfp, Zl, Sl, vsb, kmax, lmA);
  k_scan  <<<16*65, 256, 0, stream>>>(Zl, Sl, vsb, lmA, kmax, S0b, outZ, oSt);
  k_tr    <<<64,    256, 0, stream>>>(oSt, outS);
  k_outF  <<<512,   512, 76800, stream>>>(q, pjh, kfp, v, S0b, Zl, lmA, kmax, outO);
}

// Round 11
// 145.884 us; speedup vs baseline: 1.1097x; 1.1097x over previous
//
#include <hip/hip_runtime.h>

typedef unsigned short ushort_t;
typedef __attribute__((ext_vector_type(8))) short bf16x8;
typedef __attribute__((ext_vector_type(8))) _Float16 f16x8;
typedef __attribute__((ext_vector_type(16))) float f32x16;

#define NORMC 0.35355339059327373f   // 64^-0.25
#define DIAGC 0.0625f                // 0.5 * 64^-0.5
#define RATIO 0.0625f                // 256^-0.5
#define KEPS  1e-4f
#define AEPS  1e-6f
#define KAPPA (RATIO*KEPS)

__device__ __forceinline__ unsigned short f2bf(float f){
  unsigned u = __float_as_uint(f);
  unsigned r = (u + 0x7FFFu + ((u >> 16) & 1u)) >> 16;  // RNE
  return (unsigned short)r;
}
__device__ __forceinline__ float bf2f(unsigned short h){
  return __uint_as_float(((unsigned)h) << 16);
}
__device__ __forceinline__ unsigned enc_f(float f){
  unsigned u = __float_as_uint(f);
  return (u & 0x80000000u) ? ~u : (u | 0x80000000u);
}
__device__ __forceinline__ float dec_f(unsigned e){
  unsigned b = (e & 0x80000000u) ? (e ^ 0x80000000u) : ~e;
  return __uint_as_float(b);
}
__device__ __forceinline__ unsigned short h2u(_Float16 h){
  union { _Float16 h; unsigned short u; } c; c.h = h; return c.u;
}
__device__ __forceinline__ unsigned pk2h(float a, float b){
  return (unsigned)h2u((_Float16)a) | ((unsigned)h2u((_Float16)b) << 16);
}

// K0: proj -> fp16 (NORMC-scaled), layout [m][d]; init global-max slot
__global__ void k_prep(const float* __restrict__ proj, ushort_t* __restrict__ pjh,
                       unsigned* __restrict__ kmax){
  int t = threadIdx.x;   // m
  if (t == 0) *kmax = 0u;
  for (int d = 0; d < 64; ++d){
    float val = NORMC * proj[t*64 + d];
    pjh[t*64 + d] = h2u((_Float16)val);
  }
}

// K_A: k-feature GEMM + per-chunk sums (fused). One block per chunk, 512 thr / 8 waves.
// Writes kfpre (global), Sl_pre [e][m] (fp32), Zl_pre [m], vsum [e], lmArr, atomicMax gm.
__launch_bounds__(512, 2)
__global__ void k_chunkF(const float* __restrict__ kk, const float* __restrict__ v,
                         const ushort_t* __restrict__ pjh,
                         ushort_t* __restrict__ kfp, float* __restrict__ Zl,
                         float* __restrict__ Sl, float* __restrict__ vsb,
                         unsigned* __restrict__ kmax, float* __restrict__ lmArr)
{
  extern __shared__ char sm[];
  char* Bp = sm;                        // proj frag-packed [0,32K)
  char* Xh = sm + 32768;                // x-hi frags [32K,48K)
  char* Xl = sm + 49152;                // x-lo frags [48K,64K)
  char* ob = sm;                        // epilogue kfp staging alias [0,64K)
  char* kT = sm + 65536;                // [256 m][256B c] bf16, swz ^((m&15)<<4)
  char* vT = sm + 131072;               // [64 e][256B c] bf16, swz ^((e&15)<<4)
  float* dsm  = (float*)(sm + 147456);  // [128]
  float* wred = (float*)(sm + 147968);  // [8]

  int tid = threadIdx.x;
  int w   = tid >> 6;
  int wr  = w & 3;
  int wc  = w >> 2;
  int lane= tid & 63;
  int l31 = lane & 31;
  int half= lane >> 5;
  int cb  = (int)blockIdx.x;
  int bh  = cb >> 5, j = cb & 31;
  int row0 = bh*4096 + j*128;

  // stage proj frags
  for (int i = tid; i < 2048; i += 512){
    int m = i >> 3, c8 = i & 7;
    int rgn = ((m>>5)*4 + (c8>>1))*2 + (c8&1);
    int slot = (m & 31) ^ ((rgn & 7) << 2);
    *(uint4*)(Bp + rgn*512 + slot*16) = *(const uint4*)(pjh + m*64 + c8*8);
  }
  // stage x = k-chunk frags (fp16 hi/lo) + dsm
  #pragma unroll
  for (int it = 0; it < 4; ++it){
    int g = it*512 + tid;
    int row = g >> 4, c4 = g & 15;
    float4 xv = *(const float4*)(kk + (size_t)(row0+row)*64 + c4*4);
    _Float16 h0=(_Float16)xv.x, h1=(_Float16)xv.y, h2=(_Float16)xv.z, h3=(_Float16)xv.w;
    float l0 = xv.x-(float)h0, l1 = xv.y-(float)h1, l2 = xv.z-(float)h2, l3 = xv.w-(float)h3;
    int rgn = ((row>>5)*4 + (c4>>2))*2 + ((c4>>1)&1);
    int off = rgn*512 + (((row&31) ^ ((c4>>1)<<2)))*16 + (c4&1)*8;
    uint2 ph; ph.x = (unsigned)h2u(h0)|((unsigned)h2u(h1)<<16);
              ph.y = (unsigned)h2u(h2)|((unsigned)h2u(h3)<<16);
    uint2 pl; pl.x = pk2h(l0,l1); pl.y = pk2h(l2,l3);
    *(uint2*)(Xh + off) = ph;
    *(uint2*)(Xl + off) = pl;
    float ssq = xv.x*xv.x + xv.y*xv.y + xv.z*xv.z + xv.w*xv.w;
    ssq += __shfl_xor(ssq, 1); ssq += __shfl_xor(ssq, 2);
    ssq += __shfl_xor(ssq, 4); ssq += __shfl_xor(ssq, 8);
    if ((tid & 15) == 0) dsm[row] = ssq;
  }
  // stage vT (bf16 transposed)
  {
    int e = tid & 63, c0 = tid >> 6;
    int swz = (e & 15) << 4;
    #pragma unroll
    for (int u=0; u<16; ++u){
      int c = c0 + u*8;
      *(ushort_t*)(vT + e*256 + ((c*2) ^ swz)) = f2bf(v[(size_t)(row0+c)*64 + e]);
    }
  }
  __syncthreads();

  // k-dash (fp16 2-term)
  f16x8 ah[4], al[4];
  #pragma unroll
  for (int ks = 0; ks < 4; ++ks){
    int rgn = (wr*4+ks)*2+half;
    int off = rgn*512 + ((l31 ^ ((2*ks+half)<<2)))*16;
    ah[ks] = *(const f16x8*)(Xh + off);
    al[ks] = *(const f16x8*)(Xl + off);
  }
  f32x16 acc[4];
  #pragma unroll
  for (int ct=0; ct<4; ++ct){
    #pragma unroll
    for (int r=0; r<16; ++r) acc[ct][r] = 0.f;
  }
  #pragma unroll
  for (int ks = 0; ks < 4; ++ks){
    #pragma unroll
    for (int ct=0; ct<4; ++ct){
      int ctg = wc*4 + ct;
      int rgn = (ctg*4+ks)*2+half;
      f16x8 bv = *(const f16x8*)(Bp + rgn*512 + ((l31 ^ ((2*ks+half)<<2)))*16);
      acc[ct] = __builtin_amdgcn_mfma_f32_32x32x16_f16(ah[ks], bv, acc[ct], 0, 0, 0);
      acc[ct] = __builtin_amdgcn_mfma_f32_32x32x16_f16(al[ks], bv, acc[ct], 0, 0, 0);
    }
  }

  // block max
  {
    float wm = acc[0][0];
    #pragma unroll
    for (int ct=0; ct<4; ++ct){
      #pragma unroll
      for (int r=0; r<16; ++r) wm = fmaxf(wm, acc[ct][r]);
    }
    #pragma unroll
    for (int s=1; s<32; s<<=1) wm = fmaxf(wm, __shfl_xor(wm, s));
    wm = fmaxf(wm, __shfl_xor(wm, 32));
    if (lane == 0) wred[w] = wm;
  }
  __syncthreads();
  float lmb = wred[0];
  #pragma unroll
  for (int i=1;i<8;++i) lmb = fmaxf(lmb, wred[i]);
  if (tid == 0){
    lmArr[cb] = lmb;
    atomicMax(kmax, enc_f(lmb));
  }
  float dgv[16];
  #pragma unroll
  for (int r=0; r<16; ++r)
    dgv[r] = DIAGC * dsm[32*wr + (r&3) + 8*(r>>2) + 4*half];

  // epilogue: kfpre -> ob (for global store) and kT (transposed, for GEMM)
  #pragma unroll
  for (int ct=0; ct<4; ++ct){
    int m = wc*128 + ct*32 + l31;
    int swm = (m & 15) << 4;
    #pragma unroll
    for (int g=0; g<4; ++g){
      unsigned pk0=0, pk1=0;
      #pragma unroll
      for (int rr=0; rr<4; ++rr){
        int r = g*4 + rr;
        int c = 32*wr + rr + 8*g + 4*half;
        float e = __expf(acc[ct][r] - dgv[r] - lmb);
        unsigned b = f2bf(e);
        if (rr < 2) pk0 |= b << (16*rr); else pk1 |= b << (16*(rr-2));
        *(ushort_t*)(ob + c*512 + ((m*2) ^ ((c&15)<<4))) = (ushort_t)b;
      }
      int c0 = 32*wr + 8*g + 4*half;
      *(uint2*)(kT + m*256 + ((c0*2) ^ swm)) = make_uint2(pk0, pk1);
    }
  }
  __syncthreads();

  // GEMM (swapped orientation): Sl_pre[e][m] = sum_c v[e][c]*kfpre[m][c];
  // Zl_pre[m] via ones-B on kT rows; vsum[e] via ones-A (wave 0).
  f32x16 accS[2], accz, avs[2];
  #pragma unroll
  for (int et=0;et<2;++et){
    #pragma unroll
    for (int r=0;r<16;++r){ accS[et][r]=0.f; avs[et][r]=0.f; }
  }
  #pragma unroll
  for (int r=0;r<16;++r) accz[r]=0.f;
  bf16x8 onesB, onesA;
  #pragma unroll
  for (int i=0;i<8;++i){
    onesB[i] = (l31==0) ? (short)0x3F80 : (short)0;
    onesA[i] = (short)0x3F80;
  }
  int erow = (w&1)*32 + l31;
  int mc0  = ((w>>1)*2 + 0)*32 + l31;
  int mc1  = ((w>>1)*2 + 1)*32 + l31;
  int mrow = 32*w + l31;
  #pragma unroll
  for (int ks=0; ks<8; ++ks){
    int koff = ks*32 + half*16;
    bf16x8 afv = *(const bf16x8*)(vT + erow*256 + (koff ^ ((erow&15)<<4)));
    bf16x8 bk0 = *(const bf16x8*)(kT + mc0*256 + (koff ^ ((mc0&15)<<4)));
    bf16x8 bk1 = *(const bf16x8*)(kT + mc1*256 + (koff ^ ((mc1&15)<<4)));
    bf16x8 afk = *(const bf16x8*)(kT + mrow*256 + (koff ^ ((mrow&15)<<4)));
    accS[0] = __builtin_amdgcn_mfma_f32_32x32x16_bf16(afv, bk0, accS[0], 0, 0, 0);
    accS[1] = __builtin_amdgcn_mfma_f32_32x32x16_bf16(afv, bk1, accS[1], 0, 0, 0);
    accz    = __builtin_amdgcn_mfma_f32_32x32x16_bf16(afk, onesB, accz, 0, 0, 0);
    if (w == 0){
      bf16x8 bv1 = *(const bf16x8*)(vT + (32+l31)*256 + (koff ^ (((32+l31)&15)<<4)));
      avs[0] = __builtin_amdgcn_mfma_f32_32x32x16_bf16(onesA, afv, avs[0], 0, 0, 0);
      avs[1] = __builtin_amdgcn_mfma_f32_32x32x16_bf16(onesA, bv1, avs[1], 0, 0, 0);
    }
  }
  // stores: Sl [e][m] coalesced over l31
  #pragma unroll
  for (int r=0; r<16; ++r){
    int e = (w&1)*32 + (r&3) + 8*(r>>2) + 4*half;
    Sl[(size_t)cb*16384 + (size_t)e*256 + ((w>>1)*2+0)*32 + l31] = accS[0][r];
    Sl[(size_t)cb*16384 + (size_t)e*256 + ((w>>1)*2+1)*32 + l31] = accS[1][r];
  }
  if (l31 == 0){
    #pragma unroll
    for (int r=0; r<16; ++r){
      int m = 32*w + (r&3) + 8*(r>>2) + 4*half;
      Zl[(size_t)cb*256 + m] = accz[r];
    }
  }
  if (w == 0 && half == 0){
    vsb[(size_t)cb*64 + l31]      = avs[0][0];
    vsb[(size_t)cb*64 + 32 + l31] = avs[1][0];
  }
  // kfp global store from ob
  {
    ushort_t* dst = kfp + (size_t)row0*256;
    for (int i = tid; i < 4096; i += 512){
      int row = i >> 5, s = i & 31;
      uint4 d = *(const uint4*)(ob + row*512 + ((s*16) ^ ((row&15)<<4)));
      *(uint4*)(dst + (size_t)row*256 + ((s ^ (row&15)))*8) = d;
    }
  }
}

// K4: scan with alpha/kappa correction. Sl layout [cb][e][m]. grid 16*65.
// Writes S0b bf16 [pb][e][m], outSt fp32 [bh][e][m] (inclusive), Zl excl in place, outZ.
__launch_bounds__(256)
__global__ void k_scan(float* __restrict__ Zl, const float* __restrict__ Sl,
                       const float* __restrict__ vsb, const float* __restrict__ lmArr,
                       const unsigned* __restrict__ kmax,
                       ushort_t* __restrict__ S0b,
                       float* __restrict__ outZ, float* __restrict__ outSt){
  float gm = dec_f(*kmax);
  int t = threadIdx.x;
  int bh = blockIdx.x / 65;
  int s  = blockIdx.x % 65;
  if (s == 64){
    size_t base = (size_t)(bh*32)*256 + t;
    float rz = 0.f;
    #pragma unroll
    for (int j0=0;j0<32;j0+=8){
      float x[8];
      #pragma unroll
      for (int u=0;u<8;++u){
        int cbx = bh*32 + j0 + u;
        float a = RATIO * __expf(lmArr[cbx] - gm);
        x[u] = fmaf(a, Zl[base + (size_t)(j0+u)*256], KAPPA*128.f);
      }
      #pragma unroll
      for (int u=0;u<8;++u){ Zl[base + (size_t)(j0+u)*256] = rz; rz += x[u]; }
    }
    outZ[(size_t)bh*256 + t] = rz;
  } else {
    // e = s (uniform), m = t
    size_t base = (size_t)(bh*32)*16384 + (size_t)s*256 + t;
    float rs = 0.f;
    #pragma unroll
    for (int j0=0;j0<32;j0+=8){
      float x[8];
      #pragma unroll
      for (int u=0;u<8;++u){
        int cbx = bh*32 + j0 + u;
        float a = RATIO * __expf(lmArr[cbx] - gm);
        x[u] = fmaf(a, Sl[base + (size_t)(j0+u)*16384], KAPPA * vsb[(size_t)cbx*64 + s]);
      }
      #pragma unroll
      for (int u=0;u<8;++u){
        S0b[(size_t)(bh*32 + j0+u)*16384 + (size_t)s*256 + t] = f2bf(rs);
        rs += x[u];
      }
    }
    outSt[(size_t)bh*16384 + (size_t)s*256 + t] = rs;
  }
}

// K_TR: outSt [bh][e][m] -> outS [bh][m][e]. grid 64 (16 bh x 4 m-tiles).
__launch_bounds__(256)
__global__ void k_tr(const float* __restrict__ outSt, float* __restrict__ outS){
  __shared__ float tl[64][65];
  int tid = threadIdx.x;
  int bh = blockIdx.x >> 2, mt = blockIdx.x & 3;
  int m0 = mt*64;
  for (int i = tid; i < 4096; i += 256){
    int e = i >> 6, m = i & 63;
    tl[e][m] = outSt[(size_t)bh*16384 + (size_t)e*256 + m0 + m];
  }
  __syncthreads();
  for (int i = tid; i < 4096; i += 256){
    int m = i >> 6, e = i & 63;
    outS[(size_t)bh*16384 + (size_t)(m0+m)*64 + e] = tl[e][m];
  }
}

// K_B: q-feature GEMM + per-chunk output (fused, slim staging).
// launch_bounds (512,2): 256-reg budget — R10's (512,4) forced spills (VGPR=64, 146MB scratch).
__launch_bounds__(512, 2)
__global__ void k_outF(const float* __restrict__ q, const ushort_t* __restrict__ pjh,
                       const ushort_t* __restrict__ kfp, const float* __restrict__ v,
                       const ushort_t* __restrict__ S0b, const float* __restrict__ Zp,
                       const float* __restrict__ lmArr, const unsigned* __restrict__ kmax,
                       float* __restrict__ outO)
{
  extern __shared__ char sm[];
  char* Bp   = sm;                      // [0,32K) dash proj; Ab alias after
  char* Ab   = sm;                      // [128][256B] bf16, swz ^((r&15)<<4)
  char* Xh   = sm + 32768;              // [32K,48K); qft / vTb alias
  char* qft  = sm + 32768;              // [128 c][128B m-tile], swz ^((c&7)<<4)
  char* vTb  = sm + 32768;              // [64 e][256B c], swz ^((e&15)<<4)
  char* Xl   = sm + 49152;              // [48K,64K); ktb alias
  char* ktb  = sm + 49152;              // [128 i][128B m-tile], swz ^((i&7)<<4)
  char* s0t  = sm + 65536;              // [64 e][128B m-tile], swz ^((e&7)<<4)
  float* dsm = (float*)(sm + 73728);    // [128]
  float* rmx = (float*)(sm + 74240);    // [2][128]
  float* rsc = (float*)(sm + 75264);    // [2][128]
  ushort_t* z0b = (ushort_t*)(sm + 76288); // [256] bf16(Z0+eps)

  int tid = threadIdx.x;
  int w   = tid >> 6;
  int wr  = w & 3;
  int wc  = w >> 2;
  int lane= tid & 63;
  int l31 = lane & 31;
  int half= lane >> 5;
  int pb  = (int)blockIdx.x;
  int bh  = pb >> 5, j = pb & 31;
  int row0 = bh*4096 + j*128;
  size_t qbase = (size_t)row0*256;

  float gmv = dec_f(*kmax);
  float alpha = RATIO * __expf(lmArr[pb] - gmv);

  // phase 1: stage proj + q frags + dsm + z0b
  for (int i = tid; i < 2048; i += 512){
    int m = i >> 3, c8 = i & 7;
    int rgn = ((m>>5)*4 + (c8>>1))*2 + (c8&1);
    int slot = (m & 31) ^ ((rgn & 7) << 2);
    *(uint4*)(Bp + rgn*512 + slot*16) = *(const uint4*)(pjh + m*64 + c8*8);
  }
  #pragma unroll
  for (int it = 0; it < 4; ++it){
    int g = it*512 + tid;
    int row = g >> 4, c4 = g & 15;
    float4 xv = *(const float4*)(q + (size_t)(row0+row)*64 + c4*4);
    _Float16 h0=(_Float16)xv.x, h1=(_Float16)xv.y, h2=(_Float16)xv.z, h3=(_Float16)xv.w;
    float l0 = xv.x-(float)h0, l1 = xv.y-(float)h1, l2 = xv.z-(float)h2, l3 = xv.w-(float)h3;
    int rgn = ((row>>5)*4 + (c4>>2))*2 + ((c4>>1)&1);
    int off = rgn*512 + (((row&31) ^ ((c4>>1)<<2)))*16 + (c4&1)*8;
    uint2 ph; ph.x = (unsigned)h2u(h0)|((unsigned)h2u(h1)<<16);
              ph.y = (unsigned)h2u(h2)|((unsigned)h2u(h3)<<16);
    uint2 pl; pl.x = pk2h(l0,l1); pl.y = pk2h(l2,l3);
    *(uint2*)(Xh + off) = ph;
    *(uint2*)(Xl + off) = pl;
    float ssq = xv.x*xv.x + xv.y*xv.y + xv.z*xv.z + xv.w*xv.w;
    ssq += __shfl_xor(ssq, 1); ssq += __shfl_xor(ssq, 2);
    ssq += __shfl_xor(ssq, 4); ssq += __shfl_xor(ssq, 8);
    if ((tid & 15) == 0) dsm[row] = ssq;
  }
  if (tid < 256) z0b[tid] = f2bf(Zp[(size_t)pb*256 + tid] + AEPS);
  __syncthreads();

  // q-dash
  f16x8 ah[4], al[4];
  #pragma unroll
  for (int ks = 0; ks < 4; ++ks){
    int rgn = (wr*4+ks)*2+half;
    int off = rgn*512 + ((l31 ^ ((2*ks+half)<<2)))*16;
    ah[ks] = *(const f16x8*)(Xh + off);
    al[ks] = *(const f16x8*)(Xl + off);
  }
  f32x16 acc[4];
  #pragma unroll
  for (int ct=0; ct<4; ++ct){
    #pragma unroll
    for (int r=0; r<16; ++r) acc[ct][r] = 0.f;
  }
  #pragma unroll
  for (int ks = 0; ks < 4; ++ks){
    #pragma unroll
    for (int ct=0; ct<4; ++ct){
      int ctg = wc*4 + ct;
      int rgn = (ctg*4+ks)*2+half;
      f16x8 bv = *(const f16x8*)(Bp + rgn*512 + ((l31 ^ ((2*ks+half)<<2)))*16);
      acc[ct] = __builtin_amdgcn_mfma_f32_32x32x16_f16(ah[ks], bv, acc[ct], 0, 0, 0);
      acc[ct] = __builtin_amdgcn_mfma_f32_32x32x16_f16(al[ks], bv, acc[ct], 0, 0, 0);
    }
  }
  // per-row max over this wave's 128 cols -> rmx
  {
    float rmax[16];
    #pragma unroll
    for (int r=0; r<16; ++r){
      float mx = acc[0][r];
      #pragma unroll
      for (int ct=1; ct<4; ++ct) mx = fmaxf(mx, acc[ct][r]);
      #pragma unroll
      for (int s=1; s<32; s<<=1) mx = fmaxf(mx, __shfl_xor(mx, s));
      rmax[r] = mx;
    }
    if (l31 == 0){
      #pragma unroll
      for (int r=0; r<16; ++r)
        rmx[wc*128 + 32*wr + (r&3) + 8*(r>>2) + 4*half] = rmax[r];
    }
  }
  __syncthreads();

  // exp all 256 cols -> packed bf16 regs (acc dies here)
  unsigned qpk[2][16];
  #pragma unroll
  for (int r=0; r<16; ++r){
    int lrow = 32*wr + (r&3) + 8*(r>>2) + 4*half;
    float dg = DIAGC * dsm[lrow];
    float st = fmaxf(rmx[lrow], rmx[128+lrow]);
    #pragma unroll
    for (int p=0; p<2; ++p){
      float e0 = __expf(acc[2*p][r]   - dg - st);
      float e1 = __expf(acc[2*p+1][r] - dg - st);
      qpk[p][r] = (unsigned)f2bf(RATIO*(e0+KEPS)) |
                  ((unsigned)f2bf(RATIO*(e1+KEPS)) << 16);
    }
  }

  // m-loop: A_pre = qf*kfpre^T (triangle), acc2 = qf*S0, accQ = qf*[z0|ones]
  // FULLY UNROLLED so qpk indices are compile-time (rule #20).
  f32x16 accA[2], acc2, accQ;
  #pragma unroll
  for (int ct2=0;ct2<2;++ct2){
    #pragma unroll
    for (int r=0;r<16;++r) accA[ct2][r] = 0.f;
  }
  #pragma unroll
  for (int r=0;r<16;++r){ acc2[r] = 0.f; accQ[r] = 0.f; }

  int arow = 32*wr + l31;
  #pragma unroll
  for (int mt=0; mt<4; ++mt){
    int m0 = mt*64;
    __syncthreads();
    // ktb: raw kfpre uint4 copies
    #pragma unroll
    for (int u=0;u<2;++u){
      int ci = tid*2+u; int rr = ci>>3, c8 = ci&7;
      *(uint4*)(ktb + rr*128 + ((c8*16) ^ ((rr&7)<<4))) =
          *(const uint4*)(kfp + qbase + (size_t)rr*256 + m0 + c8*8);
    }
    // s0t: S0b [e][m] uint4 copies
    {
      int e = tid >> 3, c8 = tid & 7;
      *(uint4*)(s0t + e*128 + ((c8*16) ^ ((e&7)<<4))) =
          *(const uint4*)(S0b + (size_t)pb*16384 + (size_t)e*256 + m0 + c8*8);
    }
    // qf tile from packed regs (waves owning these cols); mt&1 static after unroll
    if (wc == (mt>>1)){
      #pragma unroll
      for (int r=0;r<16;++r){
        int c = 32*wr + (r&3) + 8*(r>>2) + 4*half;
        int sw = (c&7)<<4;
        *(ushort_t*)(qft + c*128 + ((l31*2) ^ sw))      = (ushort_t)(qpk[mt&1][r] & 0xffffu);
        *(ushort_t*)(qft + c*128 + (((32+l31)*2) ^ sw)) = (ushort_t)(qpk[mt&1][r] >> 16);
      }
    }
    __syncthreads();
    #pragma unroll
    for (int ks=0;ks<4;++ks){
      int ko = ks*32 + half*16;
      bf16x8 af = *(const bf16x8*)(qft + arow*128 + (ko ^ ((arow&7)<<4)));
      {
        int er = wc*32 + l31;
        bf16x8 bS = *(const bf16x8*)(s0t + er*128 + (ko ^ ((er&7)<<4)));
        acc2 = __builtin_amdgcn_mfma_f32_32x32x16_bf16(af, bS, acc2, 0, 0, 0);
      }
      {
        bf16x8 zb = {};
        if (l31 == 0) zb = *(const bf16x8*)((const char*)z0b + m0*2 + ko);
        if (l31 == 1){
          #pragma unroll
          for (int i2=0;i2<8;++i2) zb[i2] = (short)0x3F80;
        }
        accQ = __builtin_amdgcn_mfma_f32_32x32x16_bf16(af, zb, accQ, 0, 0, 0);
      }
      #pragma unroll
      for (int ct2=0;ct2<2;++ct2){
        int c = wc*2 + ct2;
        if (c <= wr){
          int br = c*32 + l31;
          bf16x8 bk = *(const bf16x8*)(ktb + br*128 + (ko ^ ((br&7)<<4)));
          accA[ct2] = __builtin_amdgcn_mfma_f32_32x32x16_bf16(af, bk, accA[ct2], 0, 0, 0);
        }
      }
    }
  }

  // extract qz / qfs per row from accQ (cols 0,1 of D)
  float qzv[16], qfsv[16];
  #pragma unroll
  for (int r=0;r<16;++r){
    qzv[r]  = __shfl(accQ[r], half*32 + 0);
    qfsv[r] = __shfl(accQ[r], half*32 + 1);
  }

  // mask + correct A, rowsums, write Ab bf16
  {
    float p[16];
    #pragma unroll
    for (int r=0;r<16;++r) p[r]=0.f;
    #pragma unroll
    for (int ct2=0;ct2<2;++ct2){
      int c = wc*2 + ct2;
      if (c <= wr){
        #pragma unroll
        for (int r=0;r<16;++r){
          int grow = 32*wr + (r&3) + 8*(r>>2) + 4*half;
          int col  = c*32 + l31;
          float mval = (col <= grow) ? fmaf(alpha, accA[ct2][r], KAPPA*qfsv[r]) : 0.f;
          p[r] += mval;
          *(ushort_t*)(Ab + grow*256 + ((col*2) ^ ((grow&15)<<4))) = f2bf(mval);
        }
      }
    }
    #pragma unroll
    for (int s2=1;s2<32;s2<<=1){
      #pragma unroll
      for (int r=0;r<16;++r) p[r] += __shfl_xor(p[r], s2);
    }
    if (l31 == 0){
      #pragma unroll
      for (int r=0;r<16;++r)
        rsc[wc*128 + 32*wr + (r&3) + 8*(r>>2) + 4*half] = p[r];
    }
  }
  __syncthreads();

  // stage vTb (over dead qft/ktb)
  {
    int e = tid & 63, c0 = tid >> 6;
    int swz = (e & 15) << 4;
    #pragma unroll
    for (int u=0; u<16; ++u){
      int c = c0 + u*8;
      *(ushort_t*)(vTb + e*256 + ((c*2) ^ swz)) = f2bf(v[(size_t)(row0+c)*64 + e]);
    }
  }
  __syncthreads();

  // A*v (triangle over ks)
  #pragma unroll
  for (int ks=0; ks<8; ++ks){
    if (ks <= 2*wr + 1){
      bf16x8 af = *(const bf16x8*)(Ab + arow*256 + ((ks*32 + half*16) ^ ((arow&15)<<4)));
      int er = wc*32 + l31;
      bf16x8 bv = *(const bf16x8*)(vTb + er*256 + ((ks*32 + half*16) ^ ((er&15)<<4)));
      acc2 = __builtin_amdgcn_mfma_f32_32x32x16_bf16(af, bv, acc2, 0, 0, 0);
    }
  }

  // epilogue: divide & store
  #pragma unroll
  for (int r=0;r<16;++r){
    int grow = 32*wr + (r&3) + 8*(r>>2) + 4*half;
    float dv = 1.0f / (rsc[grow] + rsc[128+grow] + qzv[r]);
    outO[(size_t)(row0+grow)*64 + wc*32 + l31] = acc2[r] * dv;
  }
}

extern "C" void kernel_launch(void* const* d_in, const int* in_sizes, int n_in,
                              void* d_out, int out_size, void* d_ws, size_t ws_size,
                              hipStream_t stream){
  (void)in_sizes; (void)n_in; (void)out_size; (void)ws_size;
  const float* q    = (const float*)d_in[0];
  const float* k    = (const float*)d_in[1];
  const float* v    = (const float*)d_in[2];
  const float* proj = (const float*)d_in[3];

  char* ws = (char*)d_ws;
  unsigned* kmax = (unsigned*)ws;                          // @0
  float*    lmA  = (float*)(ws + 256);                     // 2048 B
  ushort_t* pjh  = (ushort_t*)(ws + 4096);                 // 32768 B
  ushort_t* kfp  = (ushort_t*)(ws + 65792);                // 33,554,432
  float*    Zl   = (float*)(ws + 33620224);                // 524,288
  float*    Sl   = (float*)(ws + 34144512);                // 33,554,432 ([cb][e][m])
  ushort_t* S0b  = (ushort_t*)(ws + 67698944);             // 16,777,216 ([pb][e][m])
  float*    vsb  = (float*)(ws + 84476160);                // 131,072
  float*    oSt  = (float*)(ws + 84607232);                // 4,194,304 ([bh][e][m])

  float* outO = (float*)d_out;
  float* outZ = outO + (size_t)2*8*4096*64;
  float* outS = outZ + 2*8*256;

  hipFuncSetAttribute((const void*)k_chunkF, hipFuncAttributeMaxDynamicSharedMemorySize, 148480);
  hipFuncSetAttribute((const void*)k_outF,   hipFuncAttributeMaxDynamicSharedMemorySize, 76800);

  k_prep  <<<1,     256, 0, stream>>>(proj, pjh, kmax);
  k_chunkF<<<512,   512, 148480, stream>>>(k, v, pjh, kfp, Zl, Sl, vsb, kmax, lmA);
  k_scan  <<<16*65, 256, 0, stream>>>(Zl, Sl, vsb, lmA, kmax, S0b, outZ, oSt);
  k_tr    <<<64,    256, 0, stream>>>(oSt, outS);
  k_outF  <<<512,   512, 76800, stream>>>(q, pjh, kfp, v, S0b, Zl, lmA, kmax, outO);
}

// Round 12
// 108.907 us; speedup vs baseline: 1.4864x; 1.3395x over previous
//
#include <hip/hip_runtime.h>

typedef unsigned short ushort_t;
typedef __attribute__((ext_vector_type(8))) short bf16x8;
typedef __attribute__((ext_vector_type(8))) _Float16 f16x8;
typedef __attribute__((ext_vector_type(16))) float f32x16;

#define NORMC 0.35355339059327373f   // 64^-0.25
#define DIAGC 0.0625f                // 0.5 * 64^-0.5
#define RATIO 0.0625f                // 256^-0.5
#define KEPS  1e-4f
#define AEPS  1e-6f
#define KAPPA (RATIO*KEPS)

__device__ __forceinline__ unsigned short f2bf(float f){
  unsigned u = __float_as_uint(f);
  unsigned r = (u + 0x7FFFu + ((u >> 16) & 1u)) >> 16;  // RNE
  return (unsigned short)r;
}
__device__ __forceinline__ float bf2f(unsigned short h){
  return __uint_as_float(((unsigned)h) << 16);
}
__device__ __forceinline__ unsigned enc_f(float f){
  unsigned u = __float_as_uint(f);
  return (u & 0x80000000u) ? ~u : (u | 0x80000000u);
}
__device__ __forceinline__ float dec_f(unsigned e){
  unsigned b = (e & 0x80000000u) ? (e ^ 0x80000000u) : ~e;
  return __uint_as_float(b);
}
__device__ __forceinline__ unsigned short h2u(_Float16 h){
  union { _Float16 h; unsigned short u; } c; c.h = h; return c.u;
}
__device__ __forceinline__ unsigned pk2h(float a, float b){
  return (unsigned)h2u((_Float16)a) | ((unsigned)h2u((_Float16)b) << 16);
}

// K0: proj -> fp16 (NORMC-scaled), layout [m][d]; init global-max slot
__global__ void k_prep(const float* __restrict__ proj, ushort_t* __restrict__ pjh,
                       unsigned* __restrict__ kmax){
  int t = threadIdx.x;   // m
  if (t == 0) *kmax = 0u;
  for (int d = 0; d < 64; ++d){
    float val = NORMC * proj[t*64 + d];
    pjh[t*64 + d] = h2u((_Float16)val);
  }
}

// K_FQ: q-feature GEMM only (R7's proven q-path). 512 blocks, 8 waves.
// Writes qf (global, linear [row][m]) with per-row-max stabilizer.
__launch_bounds__(512, 4)
__global__ void k_featQ(const float* __restrict__ q, const ushort_t* __restrict__ pjh,
                        ushort_t* __restrict__ qf)
{
  extern __shared__ char sm[];
  char* Bp = sm;                        // proj frag-packed [0,32K)
  char* Xh = sm + 32768;                // x-hi frags
  char* Xl = sm + 49152;                // x-lo frags
  float* dsm = (float*)(sm + 65536);    // [128]
  float* rmx = (float*)(sm + 66048);    // [2][128]

  int tid = threadIdx.x;
  int w   = tid >> 6;
  int wr  = w & 3;
  int wc  = w >> 2;
  int lane= tid & 63;
  int l31 = lane & 31;
  int half= lane >> 5;
  int tile = (int)blockIdx.x;
  int row0 = tile * 128;

  for (int i = tid; i < 2048; i += 512){
    int m = i >> 3, c8 = i & 7;
    int rgn = ((m>>5)*4 + (c8>>1))*2 + (c8&1);
    int slot = (m & 31) ^ ((rgn & 7) << 2);
    *(uint4*)(Bp + rgn*512 + slot*16) = *(const uint4*)(pjh + m*64 + c8*8);
  }
  #pragma unroll
  for (int it = 0; it < 4; ++it){
    int g = it*512 + tid;
    int row = g >> 4, c4 = g & 15;
    float4 xv = *(const float4*)(q + (size_t)(row0+row)*64 + c4*4);
    _Float16 h0=(_Float16)xv.x, h1=(_Float16)xv.y, h2=(_Float16)xv.z, h3=(_Float16)xv.w;
    float l0 = xv.x-(float)h0, l1 = xv.y-(float)h1, l2 = xv.z-(float)h2, l3 = xv.w-(float)h3;
    int rgn = ((row>>5)*4 + (c4>>2))*2 + ((c4>>1)&1);
    int off = rgn*512 + (((row&31) ^ ((c4>>1)<<2)))*16 + (c4&1)*8;
    uint2 ph; ph.x = (unsigned)h2u(h0)|((unsigned)h2u(h1)<<16);
              ph.y = (unsigned)h2u(h2)|((unsigned)h2u(h3)<<16);
    uint2 pl; pl.x = pk2h(l0,l1); pl.y = pk2h(l2,l3);
    *(uint2*)(Xh + off) = ph;
    *(uint2*)(Xl + off) = pl;
    float ssq = xv.x*xv.x + xv.y*xv.y + xv.z*xv.z + xv.w*xv.w;
    ssq += __shfl_xor(ssq, 1); ssq += __shfl_xor(ssq, 2);
    ssq += __shfl_xor(ssq, 4); ssq += __shfl_xor(ssq, 8);
    if ((tid & 15) == 0) dsm[row] = ssq;
  }
  __syncthreads();

  f16x8 ah[4], al[4];
  #pragma unroll
  for (int ks = 0; ks < 4; ++ks){
    int rgn = (wr*4+ks)*2+half;
    int off = rgn*512 + ((l31 ^ ((2*ks+half)<<2)))*16;
    ah[ks] = *(const f16x8*)(Xh + off);
    al[ks] = *(const f16x8*)(Xl + off);
  }
  f32x16 acc[4];
  #pragma unroll
  for (int ct=0; ct<4; ++ct){
    #pragma unroll
    for (int r=0; r<16; ++r) acc[ct][r] = 0.f;
  }
  #pragma unroll
  for (int ks = 0; ks < 4; ++ks){
    #pragma unroll
    for (int ct=0; ct<4; ++ct){
      int ctg = wc*4 + ct;
      int rgn = (ctg*4+ks)*2+half;
      f16x8 bv = *(const f16x8*)(Bp + rgn*512 + ((l31 ^ ((2*ks+half)<<2)))*16);
      acc[ct] = __builtin_amdgcn_mfma_f32_32x32x16_f16(ah[ks], bv, acc[ct], 0, 0, 0);
      acc[ct] = __builtin_amdgcn_mfma_f32_32x32x16_f16(al[ks], bv, acc[ct], 0, 0, 0);
    }
  }
  // per-row max over this wave's 128 cols -> rmx
  {
    float rmax[16];
    #pragma unroll
    for (int r=0; r<16; ++r){
      float mx = acc[0][r];
      #pragma unroll
      for (int ct=1; ct<4; ++ct) mx = fmaxf(mx, acc[ct][r]);
      #pragma unroll
      for (int s=1; s<32; s<<=1) mx = fmaxf(mx, __shfl_xor(mx, s));
      rmax[r] = mx;
    }
    if (l31 == 0){
      #pragma unroll
      for (int r=0; r<16; ++r)
        rmx[wc*128 + 32*wr + (r&3) + 8*(r>>2) + 4*half] = rmax[r];
    }
  }
  __syncthreads();

  float dgv[16], stv[16];
  #pragma unroll
  for (int r=0; r<16; ++r){
    int lrow = 32*wr + (r&3) + 8*(r>>2) + 4*half;
    dgv[r] = DIAGC * dsm[lrow];
    stv[r] = fmaxf(rmx[lrow], rmx[128+lrow]);
  }

  char* ob = sm;   // [128 rows][512B], swizzle ^((row&15)<<4); overwrites Bp/Xh/Xl
  #pragma unroll
  for (int r=0; r<16; ++r){
    int lrow = 32*wr + (r&3) + 8*(r>>2) + 4*half;
    #pragma unroll
    for (int ct=0; ct<4; ++ct){
      int col = wc*128 + ct*32 + l31;
      float e = __expf(acc[ct][r] - dgv[r] - stv[r]);
      *(ushort_t*)(ob + lrow*512 + ((col*2) ^ ((lrow&15)<<4))) = f2bf(RATIO*(e + KEPS));
    }
  }
  __syncthreads();
  ushort_t* dst = qf + (size_t)row0*256;
  for (int i = tid; i < 4096; i += 512){
    int row = i >> 5, s = i & 31;
    uint4 d = *(const uint4*)(ob + row*512 + ((s*16) ^ ((row&15)<<4)));
    *(uint4*)(dst + (size_t)row*256 + ((s ^ (row&15)))*8) = d;  // net: linear [row][m]
  }
}

// K_A: k-feature GEMM + per-chunk sums (fused; unchanged from R8/R11 — verified).
__launch_bounds__(512, 2)
__global__ void k_chunkF(const float* __restrict__ kk, const float* __restrict__ v,
                         const ushort_t* __restrict__ pjh,
                         ushort_t* __restrict__ kfp, float* __restrict__ Zl,
                         float* __restrict__ Sl, float* __restrict__ vsb,
                         unsigned* __restrict__ kmax, float* __restrict__ lmArr)
{
  extern __shared__ char sm[];
  char* Bp = sm;
  char* Xh = sm + 32768;
  char* Xl = sm + 49152;
  char* ob = sm;
  char* kT = sm + 65536;
  char* vT = sm + 131072;
  float* dsm  = (float*)(sm + 147456);
  float* wred = (float*)(sm + 147968);

  int tid = threadIdx.x;
  int w   = tid >> 6;
  int wr  = w & 3;
  int wc  = w >> 2;
  int lane= tid & 63;
  int l31 = lane & 31;
  int half= lane >> 5;
  int cb  = (int)blockIdx.x;
  int bh  = cb >> 5, j = cb & 31;
  int row0 = bh*4096 + j*128;

  for (int i = tid; i < 2048; i += 512){
    int m = i >> 3, c8 = i & 7;
    int rgn = ((m>>5)*4 + (c8>>1))*2 + (c8&1);
    int slot = (m & 31) ^ ((rgn & 7) << 2);
    *(uint4*)(Bp + rgn*512 + slot*16) = *(const uint4*)(pjh + m*64 + c8*8);
  }
  #pragma unroll
  for (int it = 0; it < 4; ++it){
    int g = it*512 + tid;
    int row = g >> 4, c4 = g & 15;
    float4 xv = *(const float4*)(kk + (size_t)(row0+row)*64 + c4*4);
    _Float16 h0=(_Float16)xv.x, h1=(_Float16)xv.y, h2=(_Float16)xv.z, h3=(_Float16)xv.w;
    float l0 = xv.x-(float)h0, l1 = xv.y-(float)h1, l2 = xv.z-(float)h2, l3 = xv.w-(float)h3;
    int rgn = ((row>>5)*4 + (c4>>2))*2 + ((c4>>1)&1);
    int off = rgn*512 + (((row&31) ^ ((c4>>1)<<2)))*16 + (c4&1)*8;
    uint2 ph; ph.x = (unsigned)h2u(h0)|((unsigned)h2u(h1)<<16);
              ph.y = (unsigned)h2u(h2)|((unsigned)h2u(h3)<<16);
    uint2 pl; pl.x = pk2h(l0,l1); pl.y = pk2h(l2,l3);
    *(uint2*)(Xh + off) = ph;
    *(uint2*)(Xl + off) = pl;
    float ssq = xv.x*xv.x + xv.y*xv.y + xv.z*xv.z + xv.w*xv.w;
    ssq += __shfl_xor(ssq, 1); ssq += __shfl_xor(ssq, 2);
    ssq += __shfl_xor(ssq, 4); ssq += __shfl_xor(ssq, 8);
    if ((tid & 15) == 0) dsm[row] = ssq;
  }
  {
    int e = tid & 63, c0 = tid >> 6;
    int swz = (e & 15) << 4;
    #pragma unroll
    for (int u=0; u<16; ++u){
      int c = c0 + u*8;
      *(ushort_t*)(vT + e*256 + ((c*2) ^ swz)) = f2bf(v[(size_t)(row0+c)*64 + e]);
    }
  }
  __syncthreads();

  f16x8 ah[4], al[4];
  #pragma unroll
  for (int ks = 0; ks < 4; ++ks){
    int rgn = (wr*4+ks)*2+half;
    int off = rgn*512 + ((l31 ^ ((2*ks+half)<<2)))*16;
    ah[ks] = *(const f16x8*)(Xh + off);
    al[ks] = *(const f16x8*)(Xl + off);
  }
  f32x16 acc[4];
  #pragma unroll
  for (int ct=0; ct<4; ++ct){
    #pragma unroll
    for (int r=0; r<16; ++r) acc[ct][r] = 0.f;
  }
  #pragma unroll
  for (int ks = 0; ks < 4; ++ks){
    #pragma unroll
    for (int ct=0; ct<4; ++ct){
      int ctg = wc*4 + ct;
      int rgn = (ctg*4+ks)*2+half;
      f16x8 bv = *(const f16x8*)(Bp + rgn*512 + ((l31 ^ ((2*ks+half)<<2)))*16);
      acc[ct] = __builtin_amdgcn_mfma_f32_32x32x16_f16(ah[ks], bv, acc[ct], 0, 0, 0);
      acc[ct] = __builtin_amdgcn_mfma_f32_32x32x16_f16(al[ks], bv, acc[ct], 0, 0, 0);
    }
  }
  {
    float wm = acc[0][0];
    #pragma unroll
    for (int ct=0; ct<4; ++ct){
      #pragma unroll
      for (int r=0; r<16; ++r) wm = fmaxf(wm, acc[ct][r]);
    }
    #pragma unroll
    for (int s=1; s<32; s<<=1) wm = fmaxf(wm, __shfl_xor(wm, s));
    wm = fmaxf(wm, __shfl_xor(wm, 32));
    if (lane == 0) wred[w] = wm;
  }
  __syncthreads();
  float lmb = wred[0];
  #pragma unroll
  for (int i=1;i<8;++i) lmb = fmaxf(lmb, wred[i]);
  if (tid == 0){
    lmArr[cb] = lmb;
    atomicMax(kmax, enc_f(lmb));
  }
  float dgv[16];
  #pragma unroll
  for (int r=0; r<16; ++r)
    dgv[r] = DIAGC * dsm[32*wr + (r&3) + 8*(r>>2) + 4*half];

  #pragma unroll
  for (int ct=0; ct<4; ++ct){
    int m = wc*128 + ct*32 + l31;
    int swm = (m & 15) << 4;
    #pragma unroll
    for (int g=0; g<4; ++g){
      unsigned pk0=0, pk1=0;
      #pragma unroll
      for (int rr=0; rr<4; ++rr){
        int r = g*4 + rr;
        int c = 32*wr + rr + 8*g + 4*half;
        float e = __expf(acc[ct][r] - dgv[r] - lmb);
        unsigned b = f2bf(e);
        if (rr < 2) pk0 |= b << (16*rr); else pk1 |= b << (16*(rr-2));
        *(ushort_t*)(ob + c*512 + ((m*2) ^ ((c&15)<<4))) = (ushort_t)b;
      }
      int c0 = 32*wr + 8*g + 4*half;
      *(uint2*)(kT + m*256 + ((c0*2) ^ swm)) = make_uint2(pk0, pk1);
    }
  }
  __syncthreads();

  f32x16 accS[2], accz, avs[2];
  #pragma unroll
  for (int et=0;et<2;++et){
    #pragma unroll
    for (int r=0;r<16;++r){ accS[et][r]=0.f; avs[et][r]=0.f; }
  }
  #pragma unroll
  for (int r=0;r<16;++r) accz[r]=0.f;
  bf16x8 onesB, onesA;
  #pragma unroll
  for (int i=0;i<8;++i){
    onesB[i] = (l31==0) ? (short)0x3F80 : (short)0;
    onesA[i] = (short)0x3F80;
  }
  int erow = (w&1)*32 + l31;
  int mc0  = ((w>>1)*2 + 0)*32 + l31;
  int mc1  = ((w>>1)*2 + 1)*32 + l31;
  int mrow = 32*w + l31;
  #pragma unroll
  for (int ks=0; ks<8; ++ks){
    int koff = ks*32 + half*16;
    bf16x8 afv = *(const bf16x8*)(vT + erow*256 + (koff ^ ((erow&15)<<4)));
    bf16x8 bk0 = *(const bf16x8*)(kT + mc0*256 + (koff ^ ((mc0&15)<<4)));
    bf16x8 bk1 = *(const bf16x8*)(kT + mc1*256 + (koff ^ ((mc1&15)<<4)));
    bf16x8 afk = *(const bf16x8*)(kT + mrow*256 + (koff ^ ((mrow&15)<<4)));
    accS[0] = __builtin_amdgcn_mfma_f32_32x32x16_bf16(afv, bk0, accS[0], 0, 0, 0);
    accS[1] = __builtin_amdgcn_mfma_f32_32x32x16_bf16(afv, bk1, accS[1], 0, 0, 0);
    accz    = __builtin_amdgcn_mfma_f32_32x32x16_bf16(afk, onesB, accz, 0, 0, 0);
    if (w == 0){
      bf16x8 bv1 = *(const bf16x8*)(vT + (32+l31)*256 + (koff ^ (((32+l31)&15)<<4)));
      avs[0] = __builtin_amdgcn_mfma_f32_32x32x16_bf16(onesA, afv, avs[0], 0, 0, 0);
      avs[1] = __builtin_amdgcn_mfma_f32_32x32x16_bf16(onesA, bv1, avs[1], 0, 0, 0);
    }
  }
  #pragma unroll
  for (int r=0; r<16; ++r){
    int e = (w&1)*32 + (r&3) + 8*(r>>2) + 4*half;
    Sl[(size_t)cb*16384 + (size_t)e*256 + ((w>>1)*2+0)*32 + l31] = accS[0][r];
    Sl[(size_t)cb*16384 + (size_t)e*256 + ((w>>1)*2+1)*32 + l31] = accS[1][r];
  }
  if (l31 == 0){
    #pragma unroll
    for (int r=0; r<16; ++r){
      int m = 32*w + (r&3) + 8*(r>>2) + 4*half;
      Zl[(size_t)cb*256 + m] = accz[r];
    }
  }
  if (w == 0 && half == 0){
    vsb[(size_t)cb*64 + l31]      = avs[0][0];
    vsb[(size_t)cb*64 + 32 + l31] = avs[1][0];
  }
  {
    ushort_t* dst = kfp + (size_t)row0*256;
    for (int i = tid; i < 4096; i += 512){
      int row = i >> 5, s = i & 31;
      uint4 d = *(const uint4*)(ob + row*512 + ((s*16) ^ ((row&15)<<4)));
      *(uint4*)(dst + (size_t)row*256 + ((s ^ (row&15)))*8) = d;
    }
  }
}

// K4: scan with alpha/kappa correction (unchanged).
__launch_bounds__(256)
__global__ void k_scan(float* __restrict__ Zl, const float* __restrict__ Sl,
                       const float* __restrict__ vsb, const float* __restrict__ lmArr,
                       const unsigned* __restrict__ kmax,
                       ushort_t* __restrict__ S0b,
                       float* __restrict__ outZ, float* __restrict__ outSt){
  float gm = dec_f(*kmax);
  int t = threadIdx.x;
  int bh = blockIdx.x / 65;
  int s  = blockIdx.x % 65;
  if (s == 64){
    size_t base = (size_t)(bh*32)*256 + t;
    float rz = 0.f;
    #pragma unroll
    for (int j0=0;j0<32;j0+=8){
      float x[8];
      #pragma unroll
      for (int u=0;u<8;++u){
        int cbx = bh*32 + j0 + u;
        float a = RATIO * __expf(lmArr[cbx] - gm);
        x[u] = fmaf(a, Zl[base + (size_t)(j0+u)*256], KAPPA*128.f);
      }
      #pragma unroll
      for (int u=0;u<8;++u){ Zl[base + (size_t)(j0+u)*256] = rz; rz += x[u]; }
    }
    outZ[(size_t)bh*256 + t] = rz;
  } else {
    size_t base = (size_t)(bh*32)*16384 + (size_t)s*256 + t;
    float rs = 0.f;
    #pragma unroll
    for (int j0=0;j0<32;j0+=8){
      float x[8];
      #pragma unroll
      for (int u=0;u<8;++u){
        int cbx = bh*32 + j0 + u;
        float a = RATIO * __expf(lmArr[cbx] - gm);
        x[u] = fmaf(a, Sl[base + (size_t)(j0+u)*16384], KAPPA * vsb[(size_t)cbx*64 + s]);
      }
      #pragma unroll
      for (int u=0;u<8;++u){
        S0b[(size_t)(bh*32 + j0+u)*16384 + (size_t)s*256 + t] = f2bf(rs);
        rs += x[u];
      }
    }
    outSt[(size_t)bh*16384 + (size_t)s*256 + t] = rs;
  }
}

// K_TR: outSt [bh][e][m] -> outS [bh][m][e] (unchanged).
__launch_bounds__(256)
__global__ void k_tr(const float* __restrict__ outSt, float* __restrict__ outS){
  __shared__ float tl[64][65];
  int tid = threadIdx.x;
  int bh = blockIdx.x >> 2, mt = blockIdx.x & 3;
  int m0 = mt*64;
  for (int i = tid; i < 4096; i += 256){
    int e = i >> 6, m = i & 63;
    tl[e][m] = outSt[(size_t)bh*16384 + (size_t)e*256 + m0 + m];
  }
  __syncthreads();
  for (int i = tid; i < 4096; i += 256){
    int m = i >> 6, e = i & 63;
    outS[(size_t)bh*16384 + (size_t)(m0+m)*64 + e] = tl[e][m];
  }
}

// K_B: per-chunk output, NO dash phase — qf read from global.
// All staging = pure uint4 copies; alpha-correction by linearity at mask epilogue;
// qz/qfs via accQ (B = [z0|ones]). ~64 acc-regs live -> no spill at (512,2).
__launch_bounds__(512, 2)
__global__ void k_out(const ushort_t* __restrict__ qf, const ushort_t* __restrict__ kfp,
                      const float* __restrict__ v, const ushort_t* __restrict__ S0b,
                      const float* __restrict__ Zp, const float* __restrict__ lmArr,
                      const unsigned* __restrict__ kmax, float* __restrict__ outO)
{
  extern __shared__ char sm[];
  char* Ab   = sm;                      // [128][256B] bf16, swz ^((r&15)<<4)
  char* qft  = sm + 32768;              // [128 c][128B m-tile], swz ^((c&7)<<4)
  char* vTb  = sm + 32768;              // A*v phase alias: [64 e][256B], swz ^((e&15)<<4)
  char* ktb  = sm + 49152;              // [128 i][128B m-tile], swz ^((i&7)<<4)
  char* s0t  = sm + 65536;              // [64 e][128B m-tile], swz ^((e&7)<<4)
  float* rsc = (float*)(sm + 73728);    // [2][128]
  ushort_t* z0b = (ushort_t*)(sm + 74752); // [256] bf16(Z0+eps)

  int tid = threadIdx.x;
  int w   = tid >> 6;
  int wr  = w & 3;
  int wc  = w >> 2;
  int lane= tid & 63;
  int l31 = lane & 31;
  int half= lane >> 5;
  int pb  = (int)blockIdx.x;
  int bh  = pb >> 5, j = pb & 31;
  int row0 = bh*4096 + j*128;
  size_t qbase = (size_t)row0*256;

  float gmv = dec_f(*kmax);
  float alpha = RATIO * __expf(lmArr[pb] - gmv);

  if (tid < 256) z0b[tid] = f2bf(Zp[(size_t)pb*256 + tid] + AEPS);

  f32x16 accA[2], acc2, accQ;
  #pragma unroll
  for (int ct2=0;ct2<2;++ct2){
    #pragma unroll
    for (int r=0;r<16;++r) accA[ct2][r] = 0.f;
  }
  #pragma unroll
  for (int r=0;r<16;++r){ acc2[r] = 0.f; accQ[r] = 0.f; }

  int arow = 32*wr + l31;
  for (int mt=0; mt<4; ++mt){
    int m0 = mt*64;
    __syncthreads();
    // qft + ktb: pure uint4 copies from global (linear layouts)
    #pragma unroll
    for (int u=0;u<2;++u){
      int ci = tid*2+u; int rr = ci>>3, c8 = ci&7;
      int dsw = (c8*16) ^ ((rr&7)<<4);
      *(uint4*)(qft + rr*128 + dsw) = *(const uint4*)(qf  + qbase + (size_t)rr*256 + m0 + c8*8);
      *(uint4*)(ktb + rr*128 + dsw) = *(const uint4*)(kfp + qbase + (size_t)rr*256 + m0 + c8*8);
    }
    // s0t: S0b [e][m] uint4 copies
    {
      int e = tid >> 3, c8 = tid & 7;
      *(uint4*)(s0t + e*128 + ((c8*16) ^ ((e&7)<<4))) =
          *(const uint4*)(S0b + (size_t)pb*16384 + (size_t)e*256 + m0 + c8*8);
    }
    __syncthreads();
    #pragma unroll
    for (int ks=0;ks<4;++ks){
      int ko = ks*32 + half*16;
      bf16x8 af = *(const bf16x8*)(qft + arow*128 + (ko ^ ((arow&7)<<4)));
      {
        int er = wc*32 + l31;
        bf16x8 bS = *(const bf16x8*)(s0t + er*128 + (ko ^ ((er&7)<<4)));
        acc2 = __builtin_amdgcn_mfma_f32_32x32x16_bf16(af, bS, acc2, 0, 0, 0);
      }
      {
        bf16x8 zb = {};
        if (l31 == 0) zb = *(const bf16x8*)((const char*)z0b + m0*2 + ko);
        if (l31 == 1){
          #pragma unroll
          for (int i2=0;i2<8;++i2) zb[i2] = (short)0x3F80;
        }
        accQ = __builtin_amdgcn_mfma_f32_32x32x16_bf16(af, zb, accQ, 0, 0, 0);
      }
      #pragma unroll
      for (int ct2=0;ct2<2;++ct2){
        int c = wc*2 + ct2;
        if (c <= wr){
          int br = c*32 + l31;
          bf16x8 bk = *(const bf16x8*)(ktb + br*128 + (ko ^ ((br&7)<<4)));
          accA[ct2] = __builtin_amdgcn_mfma_f32_32x32x16_bf16(af, bk, accA[ct2], 0, 0, 0);
        }
      }
    }
  }

  // qz / qfs per row from accQ (cols 0,1)
  float qzv[16], qfsv[16];
  #pragma unroll
  for (int r=0;r<16;++r){
    qzv[r]  = __shfl(accQ[r], half*32 + 0);
    qfsv[r] = __shfl(accQ[r], half*32 + 1);
  }

  // mask + alpha-correct A, rowsums, write Ab bf16
  {
    float p[16];
    #pragma unroll
    for (int r=0;r<16;++r) p[r]=0.f;
    #pragma unroll
    for (int ct2=0;ct2<2;++ct2){
      int c = wc*2 + ct2;
      if (c <= wr){
        #pragma unroll
        for (int r=0;r<16;++r){
          int grow = 32*wr + (r&3) + 8*(r>>2) + 4*half;
          int col  = c*32 + l31;
          float mval = (col <= grow) ? fmaf(alpha, accA[ct2][r], KAPPA*qfsv[r]) : 0.f;
          p[r] += mval;
          *(ushort_t*)(Ab + grow*256 + ((col*2) ^ ((grow&15)<<4))) = f2bf(mval);
        }
      }
    }
    #pragma unroll
    for (int s2=1;s2<32;s2<<=1){
      #pragma unroll
      for (int r=0;r<16;++r) p[r] += __shfl_xor(p[r], s2);
    }
    if (l31 == 0){
      #pragma unroll
      for (int r=0;r<16;++r)
        rsc[wc*128 + 32*wr + (r&3) + 8*(r>>2) + 4*half] = p[r];
    }
  }
  __syncthreads();

  // stage vTb (over dead qft/ktb)
  {
    int e = tid & 63, c0 = tid >> 6;
    int swz = (e & 15) << 4;
    #pragma unroll
    for (int u=0; u<16; ++u){
      int c = c0 + u*8;
      *(ushort_t*)(vTb + e*256 + ((c*2) ^ swz)) = f2bf(v[(size_t)(row0+c)*64 + e]);
    }
  }
  __syncthreads();

  // A*v (triangle over ks; ks covers 16 k-cols, ks<=2wr+1 == cols 0..32wr+31)
  #pragma unroll
  for (int ks=0; ks<8; ++ks){
    if (ks <= 2*wr + 1){
      bf16x8 af = *(const bf16x8*)(Ab + arow*256 + ((ks*32 + half*16) ^ ((arow&15)<<4)));
      int er = wc*32 + l31;
      bf16x8 bv = *(const bf16x8*)(vTb + er*256 + ((ks*32 + half*16) ^ ((er&15)<<4)));
      acc2 = __builtin_amdgcn_mfma_f32_32x32x16_bf16(af, bv, acc2, 0, 0, 0);
    }
  }

  // epilogue: divide & store
  #pragma unroll
  for (int r=0;r<16;++r){
    int grow = 32*wr + (r&3) + 8*(r>>2) + 4*half;
    float dv = 1.0f / (rsc[grow] + rsc[128+grow] + qzv[r]);
    outO[(size_t)(row0+grow)*64 + wc*32 + l31] = acc2[r] * dv;
  }
}

extern "C" void kernel_launch(void* const* d_in, const int* in_sizes, int n_in,
                              void* d_out, int out_size, void* d_ws, size_t ws_size,
                              hipStream_t stream){
  (void)in_sizes; (void)n_in; (void)out_size; (void)ws_size;
  const float* q    = (const float*)d_in[0];
  const float* k    = (const float*)d_in[1];
  const float* v    = (const float*)d_in[2];
  const float* proj = (const float*)d_in[3];

  char* ws = (char*)d_ws;
  unsigned* kmax = (unsigned*)ws;                          // @0
  float*    lmA  = (float*)(ws + 256);                     // 2048 B
  ushort_t* pjh  = (ushort_t*)(ws + 4096);                 // 32768 B
  ushort_t* kfp  = (ushort_t*)(ws + 65792);                // 33,554,432
  float*    Zl   = (float*)(ws + 33620224);                // 524,288
  float*    Sl   = (float*)(ws + 34144512);                // 33,554,432 ([cb][e][m])
  ushort_t* S0b  = (ushort_t*)(ws + 67698944);             // 16,777,216 ([pb][e][m])
  float*    vsb  = (float*)(ws + 84476160);                // 131,072
  float*    oSt  = (float*)(ws + 84607232);                // 4,194,304 ([bh][e][m])
  ushort_t* qfb  = (ushort_t*)(ws + 88801536);             // 33,554,432

  float* outO = (float*)d_out;
  float* outZ = outO + (size_t)2*8*4096*64;
  float* outS = outZ + 2*8*256;

  hipFuncSetAttribute((const void*)k_featQ,  hipFuncAttributeMaxDynamicSharedMemorySize, 67072);
  hipFuncSetAttribute((const void*)k_chunkF, hipFuncAttributeMaxDynamicSharedMemorySize, 148480);
  hipFuncSetAttribute((const void*)k_out,    hipFuncAttributeMaxDynamicSharedMemorySize, 75264);

  k_prep  <<<1,     256, 0, stream>>>(proj, pjh, kmax);
  k_featQ <<<512,   512, 67072, stream>>>(q, pjh, qfb);
  k_chunkF<<<512,   512, 148480, stream>>>(k, v, pjh, kfp, Zl, Sl, vsb, kmax, lmA);
  k_scan  <<<16*65, 256, 0, stream>>>(Zl, Sl, vsb, lmA, kmax, S0b, outZ, oSt);
  k_tr    <<<64,    256, 0, stream>>>(oSt, outS);
  k_out   <<<512,   512, 75264, stream>>>(qfb, kfp, v, S0b, Zl, lmA, kmax, outO);
}

// Round 13
// 106.758 us; speedup vs baseline: 1.5164x; 1.0201x over previous
//
#include <hip/hip_runtime.h>

typedef unsigned short ushort_t;
typedef __attribute__((ext_vector_type(8))) short bf16x8;
typedef __attribute__((ext_vector_type(8))) _Float16 f16x8;
typedef __attribute__((ext_vector_type(16))) float f32x16;

#define NORMC 0.35355339059327373f   // 64^-0.25
#define DIAGC 0.0625f                // 0.5 * 64^-0.5
#define RATIO 0.0625f                // 256^-0.5
#define KEPS  1e-4f
#define AEPS  1e-6f
#define KAPPA (RATIO*KEPS)

__device__ __forceinline__ unsigned short f2bf(float f){
  unsigned u = __float_as_uint(f);
  unsigned r = (u + 0x7FFFu + ((u >> 16) & 1u)) >> 16;  // RNE
  return (unsigned short)r;
}
__device__ __forceinline__ float bf2f(unsigned short h){
  return __uint_as_float(((unsigned)h) << 16);
}
__device__ __forceinline__ unsigned enc_f(float f){
  unsigned u = __float_as_uint(f);
  return (u & 0x80000000u) ? ~u : (u | 0x80000000u);
}
__device__ __forceinline__ float dec_f(unsigned e){
  unsigned b = (e & 0x80000000u) ? (e ^ 0x80000000u) : ~e;
  return __uint_as_float(b);
}
__device__ __forceinline__ unsigned short h2u(_Float16 h){
  union { _Float16 h; unsigned short u; } c; c.h = h; return c.u;
}
__device__ __forceinline__ unsigned pk2h(float a, float b){
  return (unsigned)h2u((_Float16)a) | ((unsigned)h2u((_Float16)b) << 16);
}

// K0: proj -> fp16 (NORMC-scaled), layout [m][d]; init global-max slot
__global__ void k_prep(const float* __restrict__ proj, ushort_t* __restrict__ pjh,
                       unsigned* __restrict__ kmax){
  int t = threadIdx.x;   // m
  if (t == 0) *kmax = 0u;
  for (int d = 0; d < 64; ++d){
    float val = NORMC * proj[t*64 + d];
    pjh[t*64 + d] = h2u((_Float16)val);
  }
}

// K_FQ: q-feature GEMM only. 512 blocks, 8 waves. Writes qf linear [row][m].
__launch_bounds__(512, 4)
__global__ void k_featQ(const float* __restrict__ q, const ushort_t* __restrict__ pjh,
                        ushort_t* __restrict__ qf)
{
  extern __shared__ char sm[];
  char* Bp = sm;
  char* Xh = sm + 32768;
  char* Xl = sm + 49152;
  float* dsm = (float*)(sm + 65536);
  float* rmx = (float*)(sm + 66048);

  int tid = threadIdx.x;
  int w   = tid >> 6;
  int wr  = w & 3;
  int wc  = w >> 2;
  int lane= tid & 63;
  int l31 = lane & 31;
  int half= lane >> 5;
  int tile = (int)blockIdx.x;
  int row0 = tile * 128;

  for (int i = tid; i < 2048; i += 512){
    int m = i >> 3, c8 = i & 7;
    int rgn = ((m>>5)*4 + (c8>>1))*2 + (c8&1);
    int slot = (m & 31) ^ ((rgn & 7) << 2);
    *(uint4*)(Bp + rgn*512 + slot*16) = *(const uint4*)(pjh + m*64 + c8*8);
  }
  #pragma unroll
  for (int it = 0; it < 4; ++it){
    int g = it*512 + tid;
    int row = g >> 4, c4 = g & 15;
    float4 xv = *(const float4*)(q + (size_t)(row0+row)*64 + c4*4);
    _Float16 h0=(_Float16)xv.x, h1=(_Float16)xv.y, h2=(_Float16)xv.z, h3=(_Float16)xv.w;
    float l0 = xv.x-(float)h0, l1 = xv.y-(float)h1, l2 = xv.z-(float)h2, l3 = xv.w-(float)h3;
    int rgn = ((row>>5)*4 + (c4>>2))*2 + ((c4>>1)&1);
    int off = rgn*512 + (((row&31) ^ ((c4>>1)<<2)))*16 + (c4&1)*8;
    uint2 ph; ph.x = (unsigned)h2u(h0)|((unsigned)h2u(h1)<<16);
              ph.y = (unsigned)h2u(h2)|((unsigned)h2u(h3)<<16);
    uint2 pl; pl.x = pk2h(l0,l1); pl.y = pk2h(l2,l3);
    *(uint2*)(Xh + off) = ph;
    *(uint2*)(Xl + off) = pl;
    float ssq = xv.x*xv.x + xv.y*xv.y + xv.z*xv.z + xv.w*xv.w;
    ssq += __shfl_xor(ssq, 1); ssq += __shfl_xor(ssq, 2);
    ssq += __shfl_xor(ssq, 4); ssq += __shfl_xor(ssq, 8);
    if ((tid & 15) == 0) dsm[row] = ssq;
  }
  __syncthreads();

  f16x8 ah[4], al[4];
  #pragma unroll
  for (int ks = 0; ks < 4; ++ks){
    int rgn = (wr*4+ks)*2+half;
    int off = rgn*512 + ((l31 ^ ((2*ks+half)<<2)))*16;
    ah[ks] = *(const f16x8*)(Xh + off);
    al[ks] = *(const f16x8*)(Xl + off);
  }
  f32x16 acc[4];
  #pragma unroll
  for (int ct=0; ct<4; ++ct){
    #pragma unroll
    for (int r=0; r<16; ++r) acc[ct][r] = 0.f;
  }
  #pragma unroll
  for (int ks = 0; ks < 4; ++ks){
    #pragma unroll
    for (int ct=0; ct<4; ++ct){
      int ctg = wc*4 + ct;
      int rgn = (ctg*4+ks)*2+half;
      f16x8 bv = *(const f16x8*)(Bp + rgn*512 + ((l31 ^ ((2*ks+half)<<2)))*16);
      acc[ct] = __builtin_amdgcn_mfma_f32_32x32x16_f16(ah[ks], bv, acc[ct], 0, 0, 0);
      acc[ct] = __builtin_amdgcn_mfma_f32_32x32x16_f16(al[ks], bv, acc[ct], 0, 0, 0);
    }
  }
  {
    float rmax[16];
    #pragma unroll
    for (int r=0; r<16; ++r){
      float mx = acc[0][r];
      #pragma unroll
      for (int ct=1; ct<4; ++ct) mx = fmaxf(mx, acc[ct][r]);
      #pragma unroll
      for (int s=1; s<32; s<<=1) mx = fmaxf(mx, __shfl_xor(mx, s));
      rmax[r] = mx;
    }
    if (l31 == 0){
      #pragma unroll
      for (int r=0; r<16; ++r)
        rmx[wc*128 + 32*wr + (r&3) + 8*(r>>2) + 4*half] = rmax[r];
    }
  }
  __syncthreads();

  float dgv[16], stv[16];
  #pragma unroll
  for (int r=0; r<16; ++r){
    int lrow = 32*wr + (r&3) + 8*(r>>2) + 4*half;
    dgv[r] = DIAGC * dsm[lrow];
    stv[r] = fmaxf(rmx[lrow], rmx[128+lrow]);
  }

  char* ob = sm;
  #pragma unroll
  for (int r=0; r<16; ++r){
    int lrow = 32*wr + (r&3) + 8*(r>>2) + 4*half;
    #pragma unroll
    for (int ct=0; ct<4; ++ct){
      int col = wc*128 + ct*32 + l31;
      float e = __expf(acc[ct][r] - dgv[r] - stv[r]);
      *(ushort_t*)(ob + lrow*512 + ((col*2) ^ ((lrow&15)<<4))) = f2bf(RATIO*(e + KEPS));
    }
  }
  __syncthreads();
  ushort_t* dst = qf + (size_t)row0*256;
  for (int i = tid; i < 4096; i += 512){
    int row = i >> 5, s = i & 31;
    uint4 d = *(const uint4*)(ob + row*512 + ((s*16) ^ ((row&15)<<4)));
    *(uint4*)(dst + (size_t)row*256 + ((s ^ (row&15)))*8) = d;
  }
}

// K_A: k-feature GEMM + per-chunk sums (unchanged, verified).
__launch_bounds__(512, 2)
__global__ void k_chunkF(const float* __restrict__ kk, const float* __restrict__ v,
                         const ushort_t* __restrict__ pjh,
                         ushort_t* __restrict__ kfp, float* __restrict__ Zl,
                         float* __restrict__ Sl, float* __restrict__ vsb,
                         unsigned* __restrict__ kmax, float* __restrict__ lmArr)
{
  extern __shared__ char sm[];
  char* Bp = sm;
  char* Xh = sm + 32768;
  char* Xl = sm + 49152;
  char* ob = sm;
  char* kT = sm + 65536;
  char* vT = sm + 131072;
  float* dsm  = (float*)(sm + 147456);
  float* wred = (float*)(sm + 147968);

  int tid = threadIdx.x;
  int w   = tid >> 6;
  int wr  = w & 3;
  int wc  = w >> 2;
  int lane= tid & 63;
  int l31 = lane & 31;
  int half= lane >> 5;
  int cb  = (int)blockIdx.x;
  int bh  = cb >> 5, j = cb & 31;
  int row0 = bh*4096 + j*128;

  for (int i = tid; i < 2048; i += 512){
    int m = i >> 3, c8 = i & 7;
    int rgn = ((m>>5)*4 + (c8>>1))*2 + (c8&1);
    int slot = (m & 31) ^ ((rgn & 7) << 2);
    *(uint4*)(Bp + rgn*512 + slot*16) = *(const uint4*)(pjh + m*64 + c8*8);
  }
  #pragma unroll
  for (int it = 0; it < 4; ++it){
    int g = it*512 + tid;
    int row = g >> 4, c4 = g & 15;
    float4 xv = *(const float4*)(kk + (size_t)(row0+row)*64 + c4*4);
    _Float16 h0=(_Float16)xv.x, h1=(_Float16)xv.y, h2=(_Float16)xv.z, h3=(_Float16)xv.w;
    float l0 = xv.x-(float)h0, l1 = xv.y-(float)h1, l2 = xv.z-(float)h2, l3 = xv.w-(float)h3;
    int rgn = ((row>>5)*4 + (c4>>2))*2 + ((c4>>1)&1);
    int off = rgn*512 + (((row&31) ^ ((c4>>1)<<2)))*16 + (c4&1)*8;
    uint2 ph; ph.x = (unsigned)h2u(h0)|((unsigned)h2u(h1)<<16);
              ph.y = (unsigned)h2u(h2)|((unsigned)h2u(h3)<<16);
    uint2 pl; pl.x = pk2h(l0,l1); pl.y = pk2h(l2,l3);
    *(uint2*)(Xh + off) = ph;
    *(uint2*)(Xl + off) = pl;
    float ssq = xv.x*xv.x + xv.y*xv.y + xv.z*xv.z + xv.w*xv.w;
    ssq += __shfl_xor(ssq, 1); ssq += __shfl_xor(ssq, 2);
    ssq += __shfl_xor(ssq, 4); ssq += __shfl_xor(ssq, 8);
    if ((tid & 15) == 0) dsm[row] = ssq;
  }
  {
    int e = tid & 63, c0 = tid >> 6;
    int swz = (e & 15) << 4;
    #pragma unroll
    for (int u=0; u<16; ++u){
      int c = c0 + u*8;
      *(ushort_t*)(vT + e*256 + ((c*2) ^ swz)) = f2bf(v[(size_t)(row0+c)*64 + e]);
    }
  }
  __syncthreads();

  f16x8 ah[4], al[4];
  #pragma unroll
  for (int ks = 0; ks < 4; ++ks){
    int rgn = (wr*4+ks)*2+half;
    int off = rgn*512 + ((l31 ^ ((2*ks+half)<<2)))*16;
    ah[ks] = *(const f16x8*)(Xh + off);
    al[ks] = *(const f16x8*)(Xl + off);
  }
  f32x16 acc[4];
  #pragma unroll
  for (int ct=0; ct<4; ++ct){
    #pragma unroll
    for (int r=0; r<16; ++r) acc[ct][r] = 0.f;
  }
  #pragma unroll
  for (int ks = 0; ks < 4; ++ks){
    #pragma unroll
    for (int ct=0; ct<4; ++ct){
      int ctg = wc*4 + ct;
      int rgn = (ctg*4+ks)*2+half;
      f16x8 bv = *(const f16x8*)(Bp + rgn*512 + ((l31 ^ ((2*ks+half)<<2)))*16);
      acc[ct] = __builtin_amdgcn_mfma_f32_32x32x16_f16(ah[ks], bv, acc[ct], 0, 0, 0);
      acc[ct] = __builtin_amdgcn_mfma_f32_32x32x16_f16(al[ks], bv, acc[ct], 0, 0, 0);
    }
  }
  {
    float wm = acc[0][0];
    #pragma unroll
    for (int ct=0; ct<4; ++ct){
      #pragma unroll
      for (int r=0; r<16; ++r) wm = fmaxf(wm, acc[ct][r]);
    }
    #pragma unroll
    for (int s=1; s<32; s<<=1) wm = fmaxf(wm, __shfl_xor(wm, s));
    wm = fmaxf(wm, __shfl_xor(wm, 32));
    if (lane == 0) wred[w] = wm;
  }
  __syncthreads();
  float lmb = wred[0];
  #pragma unroll
  for (int i=1;i<8;++i) lmb = fmaxf(lmb, wred[i]);
  if (tid == 0){
    lmArr[cb] = lmb;
    atomicMax(kmax, enc_f(lmb));
  }
  float dgv[16];
  #pragma unroll
  for (int r=0; r<16; ++r)
    dgv[r] = DIAGC * dsm[32*wr + (r&3) + 8*(r>>2) + 4*half];

  #pragma unroll
  for (int ct=0; ct<4; ++ct){
    int m = wc*128 + ct*32 + l31;
    int swm = (m & 15) << 4;
    #pragma unroll
    for (int g=0; g<4; ++g){
      unsigned pk0=0, pk1=0;
      #pragma unroll
      for (int rr=0; rr<4; ++rr){
        int r = g*4 + rr;
        int c = 32*wr + rr + 8*g + 4*half;
        float e = __expf(acc[ct][r] - dgv[r] - lmb);
        unsigned b = f2bf(e);
        if (rr < 2) pk0 |= b << (16*rr); else pk1 |= b << (16*(rr-2));
        *(ushort_t*)(ob + c*512 + ((m*2) ^ ((c&15)<<4))) = (ushort_t)b;
      }
      int c0 = 32*wr + 8*g + 4*half;
      *(uint2*)(kT + m*256 + ((c0*2) ^ swm)) = make_uint2(pk0, pk1);
    }
  }
  __syncthreads();

  f32x16 accS[2], accz, avs[2];
  #pragma unroll
  for (int et=0;et<2;++et){
    #pragma unroll
    for (int r=0;r<16;++r){ accS[et][r]=0.f; avs[et][r]=0.f; }
  }
  #pragma unroll
  for (int r=0;r<16;++r) accz[r]=0.f;
  bf16x8 onesB, onesA;
  #pragma unroll
  for (int i=0;i<8;++i){
    onesB[i] = (l31==0) ? (short)0x3F80 : (short)0;
    onesA[i] = (short)0x3F80;
  }
  int erow = (w&1)*32 + l31;
  int mc0  = ((w>>1)*2 + 0)*32 + l31;
  int mc1  = ((w>>1)*2 + 1)*32 + l31;
  int mrow = 32*w + l31;
  #pragma unroll
  for (int ks=0; ks<8; ++ks){
    int koff = ks*32 + half*16;
    bf16x8 afv = *(const bf16x8*)(vT + erow*256 + (koff ^ ((erow&15)<<4)));
    bf16x8 bk0 = *(const bf16x8*)(kT + mc0*256 + (koff ^ ((mc0&15)<<4)));
    bf16x8 bk1 = *(const bf16x8*)(kT + mc1*256 + (koff ^ ((mc1&15)<<4)));
    bf16x8 afk = *(const bf16x8*)(kT + mrow*256 + (koff ^ ((mrow&15)<<4)));
    accS[0] = __builtin_amdgcn_mfma_f32_32x32x16_bf16(afv, bk0, accS[0], 0, 0, 0);
    accS[1] = __builtin_amdgcn_mfma_f32_32x32x16_bf16(afv, bk1, accS[1], 0, 0, 0);
    accz    = __builtin_amdgcn_mfma_f32_32x32x16_bf16(afk, onesB, accz, 0, 0, 0);
    if (w == 0){
      bf16x8 bv1 = *(const bf16x8*)(vT + (32+l31)*256 + (koff ^ (((32+l31)&15)<<4)));
      avs[0] = __builtin_amdgcn_mfma_f32_32x32x16_bf16(onesA, afv, avs[0], 0, 0, 0);
      avs[1] = __builtin_amdgcn_mfma_f32_32x32x16_bf16(onesA, bv1, avs[1], 0, 0, 0);
    }
  }
  #pragma unroll
  for (int r=0; r<16; ++r){
    int e = (w&1)*32 + (r&3) + 8*(r>>2) + 4*half;
    Sl[(size_t)cb*16384 + (size_t)e*256 + ((w>>1)*2+0)*32 + l31] = accS[0][r];
    Sl[(size_t)cb*16384 + (size_t)e*256 + ((w>>1)*2+1)*32 + l31] = accS[1][r];
  }
  if (l31 == 0){
    #pragma unroll
    for (int r=0; r<16; ++r){
      int m = 32*w + (r&3) + 8*(r>>2) + 4*half;
      Zl[(size_t)cb*256 + m] = accz[r];
    }
  }
  if (w == 0 && half == 0){
    vsb[(size_t)cb*64 + l31]      = avs[0][0];
    vsb[(size_t)cb*64 + 32 + l31] = avs[1][0];
  }
  {
    ushort_t* dst = kfp + (size_t)row0*256;
    for (int i = tid; i < 4096; i += 512){
      int row = i >> 5, s = i & 31;
      uint4 d = *(const uint4*)(ob + row*512 + ((s*16) ^ ((row&15)<<4)));
      *(uint4*)(dst + (size_t)row*256 + ((s ^ (row&15)))*8) = d;
    }
  }
}

// K4: scan with alpha/kappa correction (unchanged).
__launch_bounds__(256)
__global__ void k_scan(float* __restrict__ Zl, const float* __restrict__ Sl,
                       const float* __restrict__ vsb, const float* __restrict__ lmArr,
                       const unsigned* __restrict__ kmax,
                       ushort_t* __restrict__ S0b,
                       float* __restrict__ outZ, float* __restrict__ outSt){
  float gm = dec_f(*kmax);
  int t = threadIdx.x;
  int bh = blockIdx.x / 65;
  int s  = blockIdx.x % 65;
  if (s == 64){
    size_t base = (size_t)(bh*32)*256 + t;
    float rz = 0.f;
    #pragma unroll
    for (int j0=0;j0<32;j0+=8){
      float x[8];
      #pragma unroll
      for (int u=0;u<8;++u){
        int cbx = bh*32 + j0 + u;
        float a = RATIO * __expf(lmArr[cbx] - gm);
        x[u] = fmaf(a, Zl[base + (size_t)(j0+u)*256], KAPPA*128.f);
      }
      #pragma unroll
      for (int u=0;u<8;++u){ Zl[base + (size_t)(j0+u)*256] = rz; rz += x[u]; }
    }
    outZ[(size_t)bh*256 + t] = rz;
  } else {
    size_t base = (size_t)(bh*32)*16384 + (size_t)s*256 + t;
    float rs = 0.f;
    #pragma unroll
    for (int j0=0;j0<32;j0+=8){
      float x[8];
      #pragma unroll
      for (int u=0;u<8;++u){
        int cbx = bh*32 + j0 + u;
        float a = RATIO * __expf(lmArr[cbx] - gm);
        x[u] = fmaf(a, Sl[base + (size_t)(j0+u)*16384], KAPPA * vsb[(size_t)cbx*64 + s]);
      }
      #pragma unroll
      for (int u=0;u<8;++u){
        S0b[(size_t)(bh*32 + j0+u)*16384 + (size_t)s*256 + t] = f2bf(rs);
        rs += x[u];
      }
    }
    outSt[(size_t)bh*16384 + (size_t)s*256 + t] = rs;
  }
}

// K_TR: outSt [bh][e][m] -> outS [bh][m][e] (unchanged).
__launch_bounds__(256)
__global__ void k_tr(const float* __restrict__ outSt, float* __restrict__ outS){
  __shared__ float tl[64][65];
  int tid = threadIdx.x;
  int bh = blockIdx.x >> 2, mt = blockIdx.x & 3;
  int m0 = mt*64;
  for (int i = tid; i < 4096; i += 256){
    int e = i >> 6, m = i & 63;
    tl[e][m] = outSt[(size_t)bh*16384 + (size_t)e*256 + m0 + m];
  }
  __syncthreads();
  for (int i = tid; i < 4096; i += 256){
    int m = i >> 6, e = i & 63;
    outS[(size_t)bh*16384 + (size_t)(m0+m)*64 + e] = tl[e][m];
  }
}

// K_B: per-chunk output with T14 register-prefetch pipeline.
// Per m-tile: barrier -> ds_write(prefetched regs) -> barrier -> issue loads(mt+1) -> MFMA(mt).
// v preloaded into regs at entry. All staging pure copies; alpha-correction at epilogue.
__launch_bounds__(512, 2)
__global__ void k_out(const ushort_t* __restrict__ qf, const ushort_t* __restrict__ kfp,
                      const float* __restrict__ v, const ushort_t* __restrict__ S0b,
                      const float* __restrict__ Zp, const float* __restrict__ lmArr,
                      const unsigned* __restrict__ kmax, float* __restrict__ outO)
{
  extern __shared__ char sm[];
  char* Ab   = sm;                      // [128][256B] bf16, swz ^((r&15)<<4)
  char* qft  = sm + 32768;              // [128 c][128B m-tile], swz ^((c&7)<<4)
  char* vTb  = sm + 32768;              // A*v phase alias: [64 e][256B], swz ^((e&15)<<4)
  char* ktb  = sm + 49152;              // [128 i][128B m-tile], swz ^((i&7)<<4)
  char* s0t  = sm + 65536;              // [64 e][128B m-tile], swz ^((e&7)<<4)
  float* rsc = (float*)(sm + 73728);    // [2][128]
  ushort_t* z0b = (ushort_t*)(sm + 74752); // [256] bf16(Z0+eps)

  int tid = threadIdx.x;
  int w   = tid >> 6;
  int wr  = w & 3;
  int wc  = w >> 2;
  int lane= tid & 63;
  int l31 = lane & 31;
  int half= lane >> 5;
  int pb  = (int)blockIdx.x;
  int bh  = pb >> 5, j = pb & 31;
  int row0 = bh*4096 + j*128;
  size_t qbase = (size_t)row0*256;

  float gmv = dec_f(*kmax);
  float alpha = RATIO * __expf(lmArr[pb] - gmv);

  if (tid < 256) z0b[tid] = f2bf(Zp[(size_t)pb*256 + tid] + AEPS);

  // preload v into regs (for the A*v stage at the end)
  int ve = tid & 63, vc0 = tid >> 6;
  float vld[16];
  #pragma unroll
  for (int u=0; u<16; ++u)
    vld[u] = v[(size_t)(row0 + vc0 + u*8)*64 + ve];

  // prefetch addressing (static per thread)
  int rr0 = (tid*2)   >> 3, c80 = (tid*2)   & 7;
  int rr1 = (tid*2+1) >> 3, c81 = (tid*2+1) & 7;
  int se  = tid >> 3,  sc8 = tid & 7;
  int dsw0 = (c80*16) ^ ((rr0&7)<<4);
  int dsw1 = (c81*16) ^ ((rr1&7)<<4);
  int dsws = (sc8*16) ^ ((se&7)<<4);

  uint4 pq0, pq1, pk0v, pk1v, ps0v;
  #define LOADT(m0_) do { \
    pq0  = *(const uint4*)(qf  + qbase + (size_t)rr0*256 + (m0_) + c80*8); \
    pq1  = *(const uint4*)(qf  + qbase + (size_t)rr1*256 + (m0_) + c81*8); \
    pk0v = *(const uint4*)(kfp + qbase + (size_t)rr0*256 + (m0_) + c80*8); \
    pk1v = *(const uint4*)(kfp + qbase + (size_t)rr1*256 + (m0_) + c81*8); \
    ps0v = *(const uint4*)(S0b + (size_t)pb*16384 + (size_t)se*256 + (m0_) + sc8*8); \
  } while(0)

  f32x16 accA[2], acc2, accQ;
  #pragma unroll
  for (int ct2=0;ct2<2;++ct2){
    #pragma unroll
    for (int r=0;r<16;++r) accA[ct2][r] = 0.f;
  }
  #pragma unroll
  for (int r=0;r<16;++r){ acc2[r] = 0.f; accQ[r] = 0.f; }

  int arow = 32*wr + l31;
  LOADT(0);

  #pragma unroll
  for (int mt=0; mt<4; ++mt){
    int m0 = mt*64;
    __syncthreads();                 // previous tile's LDS reads done (and z0b visible at mt=0)
    *(uint4*)(qft + rr0*128 + dsw0) = pq0;
    *(uint4*)(qft + rr1*128 + dsw1) = pq1;
    *(uint4*)(ktb + rr0*128 + dsw0) = pk0v;
    *(uint4*)(ktb + rr1*128 + dsw1) = pk1v;
    *(uint4*)(s0t + se*128  + dsws) = ps0v;
    __syncthreads();                 // tile ready
    if (mt < 3) LOADT((mt+1)*64);    // issue next-tile loads; complete under MFMA
    #pragma unroll
    for (int ks=0;ks<4;++ks){
      int ko = ks*32 + half*16;
      bf16x8 af = *(const bf16x8*)(qft + arow*128 + (ko ^ ((arow&7)<<4)));
      {
        int er = wc*32 + l31;
        bf16x8 bS = *(const bf16x8*)(s0t + er*128 + (ko ^ ((er&7)<<4)));
        acc2 = __builtin_amdgcn_mfma_f32_32x32x16_bf16(af, bS, acc2, 0, 0, 0);
      }
      {
        bf16x8 zb = {};
        if (l31 == 0) zb = *(const bf16x8*)((const char*)z0b + m0*2 + ko);
        if (l31 == 1){
          #pragma unroll
          for (int i2=0;i2<8;++i2) zb[i2] = (short)0x3F80;
        }
        accQ = __builtin_amdgcn_mfma_f32_32x32x16_bf16(af, zb, accQ, 0, 0, 0);
      }
      #pragma unroll
      for (int ct2=0;ct2<2;++ct2){
        int c = wc*2 + ct2;
        if (c <= wr){
          int br = c*32 + l31;
          bf16x8 bk = *(const bf16x8*)(ktb + br*128 + (ko ^ ((br&7)<<4)));
          accA[ct2] = __builtin_amdgcn_mfma_f32_32x32x16_bf16(af, bk, accA[ct2], 0, 0, 0);
        }
      }
    }
  }
  #undef LOADT

  // qz / qfs per row from accQ (cols 0,1)
  float qzv[16], qfsv[16];
  #pragma unroll
  for (int r=0;r<16;++r){
    qzv[r]  = __shfl(accQ[r], half*32 + 0);
    qfsv[r] = __shfl(accQ[r], half*32 + 1);
  }

  // mask + alpha-correct A, rowsums, write Ab bf16
  {
    float p[16];
    #pragma unroll
    for (int r=0;r<16;++r) p[r]=0.f;
    #pragma unroll
    for (int ct2=0;ct2<2;++ct2){
      int c = wc*2 + ct2;
      if (c <= wr){
        #pragma unroll
        for (int r=0;r<16;++r){
          int grow = 32*wr + (r&3) + 8*(r>>2) + 4*half;
          int col  = c*32 + l31;
          float mval = (col <= grow) ? fmaf(alpha, accA[ct2][r], KAPPA*qfsv[r]) : 0.f;
          p[r] += mval;
          *(ushort_t*)(Ab + grow*256 + ((col*2) ^ ((grow&15)<<4))) = f2bf(mval);
        }
      }
    }
    #pragma unroll
    for (int s2=1;s2<32;s2<<=1){
      #pragma unroll
      for (int r=0;r<16;++r) p[r] += __shfl_xor(p[r], s2);
    }
    if (l31 == 0){
      #pragma unroll
      for (int r=0;r<16;++r)
        rsc[wc*128 + 32*wr + (r&3) + 8*(r>>2) + 4*half] = p[r];
    }
  }
  __syncthreads();

  // stage vTb from preloaded regs (no global latency here)
  {
    int swz = (ve & 15) << 4;
    #pragma unroll
    for (int u=0; u<16; ++u){
      int c = vc0 + u*8;
      *(ushort_t*)(vTb + ve*256 + ((c*2) ^ swz)) = f2bf(vld[u]);
    }
  }
  __syncthreads();

  // A*v (triangle over ks)
  #pragma unroll
  for (int ks=0; ks<8; ++ks){
    if (ks <= 2*wr + 1){
      bf16x8 af = *(const bf16x8*)(Ab + arow*256 + ((ks*32 + half*16) ^ ((arow&15)<<4)));
      int er = wc*32 + l31;
      bf16x8 bv = *(const bf16x8*)(vTb + er*256 + ((ks*32 + half*16) ^ ((er&15)<<4)));
      acc2 = __builtin_amdgcn_mfma_f32_32x32x16_bf16(af, bv, acc2, 0, 0, 0);
    }
  }

  // epilogue: divide & store
  #pragma unroll
  for (int r=0;r<16;++r){
    int grow = 32*wr + (r&3) + 8*(r>>2) + 4*half;
    float dv = 1.0f / (rsc[grow] + rsc[128+grow] + qzv[r]);
    outO[(size_t)(row0+grow)*64 + wc*32 + l31] = acc2[r] * dv;
  }
}

extern "C" void kernel_launch(void* const* d_in, const int* in_sizes, int n_in,
                              void* d_out, int out_size, void* d_ws, size_t ws_size,
                              hipStream_t stream){
  (void)in_sizes; (void)n_in; (void)out_size; (void)ws_size;
  const float* q    = (const float*)d_in[0];
  const float* k    = (const float*)d_in[1];
  const float* v    = (const float*)d_in[2];
  const float* proj = (const float*)d_in[3];

  char* ws = (char*)d_ws;
  unsigned* kmax = (unsigned*)ws;                          // @0
  float*    lmA  = (float*)(ws + 256);                     // 2048 B
  ushort_t* pjh  = (ushort_t*)(ws + 4096);                 // 32768 B
  ushort_t* kfp  = (ushort_t*)(ws + 65792);                // 33,554,432
  float*    Zl   = (float*)(ws + 33620224);                // 524,288
  float*    Sl   = (float*)(ws + 34144512);                // 33,554,432 ([cb][e][m])
  ushort_t* S0b  = (ushort_t*)(ws + 67698944);             // 16,777,216 ([pb][e][m])
  float*    vsb  = (float*)(ws + 84476160);                // 131,072
  float*    oSt  = (float*)(ws + 84607232);                // 4,194,304 ([bh][e][m])
  ushort_t* qfb  = (ushort_t*)(ws + 88801536);             // 33,554,432

  float* outO = (float*)d_out;
  float* outZ = outO + (size_t)2*8*4096*64;
  float* outS = outZ + 2*8*256;

  hipFuncSetAttribute((const void*)k_featQ,  hipFuncAttributeMaxDynamicSharedMemorySize, 67072);
  hipFuncSetAttribute((const void*)k_chunkF, hipFuncAttributeMaxDynamicSharedMemorySize, 148480);
  hipFuncSetAttribute((const void*)k_out,    hipFuncAttributeMaxDynamicSharedMemorySize, 75264);

  k_prep  <<<1,     256, 0, stream>>>(proj, pjh, kmax);
  k_featQ <<<512,   512, 67072, stream>>>(q, pjh, qfb);
  k_chunkF<<<512,   512, 148480, stream>>>(k, v, pjh, kfp, Zl, Sl, vsb, kmax, lmA);
  k_scan  <<<16*65, 256, 0, stream>>>(Zl, Sl, vsb, lmA, kmax, S0b, outZ, oSt);
  k_tr    <<<64,    256, 0, stream>>>(oSt, outS);
  k_out   <<<512,   512, 75264, stream>>>(qfb, kfp, v, S0b, Zl, lmA, kmax, outO);
}